// Round 3
// baseline (4468.345 us; speedup 1.0000x reference)
//
#include <hip/hip_runtime.h>
#include <math.h>

#define TT 6
#define FC 24
#define KN 35
#define HW 65536
#define NPIX (TT*HW)   // 393216
#define CPB 16         // columns per block in col-FFT

__device__ inline float2 cmulf(float2 a, float2 b){
    return make_float2(a.x*b.x - a.y*b.y, a.x*b.y + a.y*b.x);
}

// ---------------- reduction: sum|X|^2 and sum(mask) ----------------
__global__ void reduce_kernel(const float* xr, const float* xi, const float* mask, float* sums){
    __shared__ float s1[256], s2[256];
    int tid = threadIdx.x;
    int gid = blockIdx.x*256 + tid;
    float a = 0.f, b = 0.f;
    for (int i = gid; i < NPIX; i += gridDim.x*256) a += xr[i]*xr[i] + xi[i]*xi[i];
    for (int i = gid; i < TT*256; i += gridDim.x*256) b += mask[i];
    s1[tid]=a; s2[tid]=b; __syncthreads();
    for (int off=128; off>0; off>>=1){
        if (tid<off){ s1[tid]+=s1[tid+off]; s2[tid]+=s2[tid+off]; }
        __syncthreads();
    }
    if (tid==0){ atomicAdd(&sums[0], s1[0]); atomicAdd(&sums[1], s2[0]); }
}

// ---------------- normalize: Xks = (xr + i xi)/norm ----------------
__global__ void normalize_kernel(const float* xr, const float* xi, const float* sums, float2* Xks){
    int i = blockIdx.x*256 + threadIdx.x;
    float inv = rsqrtf(sums[0]/sums[1]);
    Xks[i] = make_float2(xr[i]*inv, xi[i]*inv);
}

// ---------------- weight repack: fwd [l][tap][f][ri], adj [l][f][tap-flipped][ri] ----------------
__global__ void repack_kernel(const float* kr, const float* ki, float* Wf, float* Wa){
    int i = blockIdx.x*256 + threadIdx.x;
    if (i >= 8*121*24) return;
    int f   = i % 24;
    int tap = (i/24) % 121;
    int l   = i/(24*121);
    long src = (long)(l*24+f)*121;
    Wf[(((long)l*121+tap)*24+f)*2+0] = kr[src+tap];
    Wf[(((long)l*121+tap)*24+f)*2+1] = ki[src+tap];
    Wa[(((long)l*24+f)*121+tap)*2+0] = kr[src+120-tap];   // spatial flip baked in
    Wa[(((long)l*24+f)*121+tap)*2+1] = ki[src+120-tap];
}

// ---------------- FFT row pass (along W), centered, 2 lines/block ----------------
__global__ void fft_row_kernel(const float2* __restrict__ in, float2* __restrict__ out,
                               float dir, float scale){
    __shared__ float2 lds[2][256];
    __shared__ float2 tw[128];
    int tid = threadIdx.x;
    int line = tid >> 7;
    int j = tid & 127;
    if (tid < 128){
        float s, c;
        sincosf(dir * 6.283185307179586f * (float)tid / 256.0f, &s, &c);
        tw[tid] = make_float2(c, s);
    }
    long gline = (long)blockIdx.x*2 + line;
    const float2* src = in + gline*256;
    {
        float sg = (j & 1) ? -1.f : 1.f;
        float2 a = src[j];
        float2 b = src[j+128];
        lds[line][j]     = make_float2(a.x*sg, a.y*sg);
        lds[line][j+128] = make_float2(b.x*sg, b.y*sg);
    }
    __syncthreads();
    for (int s = 0; s < 8; s++){
        int half = 128 >> s;
        int pos = j & (half-1);
        int grp = j >> (7-s);
        int i0 = (grp << (8-s)) + pos;
        int i1 = i0 + half;
        float2 u = lds[line][i0], v = lds[line][i1];
        float2 w = tw[pos << s];
        lds[line][i0] = make_float2(u.x+v.x, u.y+v.y);
        float2 d = make_float2(u.x-v.x, u.y-v.y);
        lds[line][i1] = cmulf(d, w);
        __syncthreads();
    }
    float2* dst = out + gline*256;
    {
        int k = j;
        float sg = (k & 1) ? -scale : scale;
        float2 v = lds[line][__brev((unsigned)k) >> 24];
        dst[k] = make_float2(v.x*sg, v.y*sg);
        k = j + 128;
        sg = (k & 1) ? -scale : scale;
        v = lds[line][__brev((unsigned)k) >> 24];
        dst[k] = make_float2(v.x*sg, v.y*sg);
    }
}

// ---------------- FFT col pass (along H), centered, 16 cols/block ----------------
__global__ void fft_col_kernel(const float2* __restrict__ in, float2* __restrict__ out,
                               float dir, float scale, const float* k0 /*nullable*/){
    __shared__ float2 lds[256][CPB+1];
    __shared__ float2 tw[128];
    int tid = threadIdx.x;
    if (tid < 128){
        float s, c;
        sincosf(dir * 6.283185307179586f * (float)tid / 256.0f, &s, &c);
        tw[tid] = make_float2(c, s);
    }
    int t  = blockIdx.x / (256/CPB);
    int w0 = (blockIdx.x % (256/CPB)) * CPB;
    const float2* src = in + (long)t*HW;
    float2* dst = out + (long)t*HW;
    int c  = tid & (CPB-1);
    int h0 = tid >> 4;
    for (int i = 0; i < 16; i++){
        int h = h0 + 16*i;
        float2 v = src[h*256 + w0 + c];
        float sg = (h & 1) ? -1.f : 1.f;
        lds[h][c] = make_float2(v.x*sg, v.y*sg);
    }
    __syncthreads();
    int jb = tid >> 4;
    for (int s = 0; s < 8; s++){
        int half = 128 >> s;
        for (int i = 0; i < 8; i++){
            int j = jb + 16*i;
            int pos = j & (half-1);
            int grp = j >> (7-s);
            int i0 = (grp << (8-s)) + pos;
            int i1 = i0 + half;
            float2 u = lds[i0][c], v = lds[i1][c];
            float2 w = tw[pos << s];
            lds[i0][c] = make_float2(u.x+v.x, u.y+v.y);
            float2 d = make_float2(u.x-v.x, u.y-v.y);
            lds[i1][c] = cmulf(d, w);
        }
        __syncthreads();
    }
    float mul = scale;
    if (k0) mul *= *k0;
    for (int i = 0; i < 16; i++){
        int k = h0 + 16*i;
        float2 v = lds[__brev((unsigned)k) >> 24][c];
        float sg = (k & 1) ? -mul : mul;
        dst[k*256 + w0 + c] = make_float2(v.x*sg, v.y*sg);
    }
}

// ---------------- fused forward conv (1->24) + spline act, writes V = DX*act ----
// z = f-quarter q (0..3): global f in [6q,6q+6). Block does ALL 6 t for a 16x16 tile,
// so the t-sum for the activation is available in registers after the tap loop.
// weights: wt[tap*48 + 2f] (f contiguous per tap -> s_load)
__global__ __launch_bounds__(256,4) void conv_fwd_act_kernel(
        const float2* __restrict__ Ximg, const float* __restrict__ wt,
        const float* __restrict__ knots, float2* __restrict__ V){
    __shared__ float2 xt[6][26][26];
    int q  = blockIdx.z;
    int h0 = blockIdx.y*16, w0 = blockIdx.x*16;
    int tx = threadIdx.x & 15, ty = threadIdx.x >> 4;
    for (int t = 0; t < 6; t++){
        const float2* src = Ximg + (long)t*HW;
        for (int i = threadIdx.x; i < 676; i += 256){
            int yy = i / 26, xx = i - yy*26;
            int gh = h0 + yy - 5, gw = w0 + xx - 5;
            float2 v = make_float2(0.f, 0.f);
            if (gh >= 0 && gh < 256 && gw >= 0 && gw < 256) v = src[gh*256 + gw];
            xt[t][yy][xx] = v;
        }
    }
    __syncthreads();
    float accx[6][6], accy[6][6];   // [f][t]
    #pragma unroll
    for (int f = 0; f < 6; f++)
        #pragma unroll
        for (int t = 0; t < 6; t++){ accx[f][t] = 0.f; accy[f][t] = 0.f; }
    for (int ky = 0; ky < 11; ky++){
        #pragma unroll
        for (int kx = 0; kx < 11; kx++){
            const float* wp = wt + (ky*11 + kx)*48 + q*12;
            float2 a[6];
            #pragma unroll
            for (int t = 0; t < 6; t++) a[t] = xt[t][ty+ky][tx+kx];
            #pragma unroll
            for (int f = 0; f < 6; f++){
                float wr = wp[2*f];
                float wi = wp[2*f+1];
                #pragma unroll
                for (int t = 0; t < 6; t++){
                    accx[f][t] = fmaf(a[t].x, wr, fmaf(-a[t].y, wi, accx[f][t]));
                    accy[f][t] = fmaf(a[t].x, wi, fmaf( a[t].y, wr, accy[f][t]));
                }
            }
        }
    }
    int h = h0 + ty, w = w0 + tx;
    #pragma unroll
    for (int f = 0; f < 6; f++){
        int fg = q*6 + f;
        float s = 0.f;
        #pragma unroll
        for (int t = 0; t < 6; t++) s += accx[f][t]*accx[f][t] + accy[f][t]*accy[f][t];
        float act_in = sqrtf(s) * (1.0f/6.0f);
        float pos = fminf(fmaxf(act_in * 34.0f, 0.0f), 34.0f);
        int i0 = (int)pos; if (i0 > 33) i0 = 33;
        float frac = pos - (float)i0;
        float k0v = knots[i0*24 + fg];
        float k1v = knots[(i0+1)*24 + fg];
        float aout = k0v*(1.0f - frac) + k1v*frac;
        #pragma unroll
        for (int t = 0; t < 6; t++)
            V[((long)(t*24+fg))*HW + h*256 + w] = make_float2(accx[f][t]*aout, accy[f][t]*aout);
    }
}

// ---------------- adjoint complex conv 24->1, double-buffered channel pipeline ----
// z = part*6 + t ; part handles f in [part*12, part*12+12), writes rg + part*NPIX
// weights: wa[f*242 + tap*2 + {0,1}] with spatial flip pre-applied
__global__ __launch_bounds__(256) void conv_adj_kernel(const float2* __restrict__ V,
                                                       const float* __restrict__ wa,
                                                       float2* __restrict__ rg){
    __shared__ float2 vt[2][74][26];
    int z = blockIdx.z;
    int t = z % 6, part = z / 6;
    int h0 = blockIdx.y*64, w0 = blockIdx.x*16;
    int tx = threadIdx.x & 15;
    int r0 = (threadIdx.x >> 4) * 4;   // 0..60
    int f0 = part*12;

    // per-thread staging slots (fixed across channels)
    int idx[8];
    #pragma unroll
    for (int j = 0; j < 8; j++){
        int i = threadIdx.x + j*256;
        int yy = i / 26, xx = i - yy*26;
        int gh = h0 + yy - 5, gw = w0 + xx - 5;
        bool ok = (i < 74*26) && gh >= 0 && gh < 256 && gw >= 0 && gw < 256;
        idx[j] = ok ? (gh*256 + gw) : -1;
    }
    float2 regs[8];
    {   // prologue: load channel f0, fill buffer 0
        const float2* src = V + ((long)(t*24+f0))*HW;
        #pragma unroll
        for (int j = 0; j < 8; j++)
            regs[j] = (idx[j] >= 0) ? src[idx[j]] : make_float2(0.f, 0.f);
        #pragma unroll
        for (int j = 0; j < 8; j++){
            int i = threadIdx.x + j*256;
            if (i < 74*26) (&vt[0][0][0])[i] = regs[j];
        }
    }
    float2 acc[4];
    #pragma unroll
    for (int r = 0; r < 4; r++) acc[r] = make_float2(0.f, 0.f);

    #pragma unroll 1
    for (int k = 0; k < 12; k++){
        int f = f0 + k;
        int buf = k & 1;
        if (k + 1 < 12){   // issue next channel's global loads (overlap with compute)
            const float2* src = V + ((long)(t*24+f+1))*HW;
            #pragma unroll
            for (int j = 0; j < 8; j++)
                regs[j] = (idx[j] >= 0) ? src[idx[j]] : make_float2(0.f, 0.f);
        }
        __syncthreads();   // vt[buf] ready for everyone
        const float* wf = wa + f*242;
        #pragma unroll
        for (int sr = 0; sr < 14; sr++){
            float2 v[11];
            #pragma unroll
            for (int kx = 0; kx < 11; kx++) v[kx] = vt[buf][r0+sr][tx+kx];
            #pragma unroll
            for (int rr = 0; rr < 4; rr++){
                int ky = sr - rr;
                if (ky < 0 || ky > 10) continue;   // compile-time resolved
                #pragma unroll
                for (int kx = 0; kx < 11; kx++){
                    float wr = wf[(ky*11+kx)*2+0];
                    float wi = wf[(ky*11+kx)*2+1];
                    acc[rr].x = fmaf(v[kx].x, wr, fmaf( v[kx].y, wi, acc[rr].x));
                    acc[rr].y = fmaf(v[kx].y, wr, fmaf(-v[kx].x, wi, acc[rr].y));
                }
            }
        }
        if (k + 1 < 12){   // drain prefetched regs into the other buffer
            #pragma unroll
            for (int j = 0; j < 8; j++){
                int i = threadIdx.x + j*256;
                if (i < 74*26) (&vt[buf^1][0][0])[i] = regs[j];
            }
        }
    }
    float2* out = rg + (long)part*NPIX + (long)t*HW;
    #pragma unroll
    for (int rr = 0; rr < 4; rr++)
        out[(h0 + r0 + rr)*256 + (w0 + tx)] = acc[rr];
}

// ---------------- k-space mask + subtract ----------------
__global__ void masksub_kernel(float2* __restrict__ tmp, const float* __restrict__ mask,
                               const float2* __restrict__ Xks){
    int i = blockIdx.x*256 + threadIdx.x;
    int t = i >> 16;
    int w = i & 255;
    float mv = mask[t*256 + w];
    float2 v = tmp[i], x = Xks[i];
    tmp[i] = make_float2(v.x*mv - x.x, v.y*mv - x.y);
}

// ---------------- momentum update (rg = rg0 + rg1 partials) ----------------
__global__ void update_kernel(float2* __restrict__ Ximg, float2* __restrict__ m,
                              const float2* __restrict__ dg, const float2* __restrict__ rg,
                              const float* __restrict__ alphas, const float* __restrict__ moms, int l){
    int i = blockIdx.x*256 + threadIdx.x;
    float a  = alphas[l];
    float mu = moms[l];
    float2 r0 = rg[i], r1 = rg[i + NPIX];
    float2 g  = make_float2(fmaf(a, dg[i].x, r0.x + r1.x), fmaf(a, dg[i].y, r0.y + r1.y));
    float2 mm = make_float2(fmaf(mu, m[i].x, g.x),         fmaf(mu, m[i].y, g.y));
    m[i] = mm;
    float2 xi = Ximg[i];
    Ximg[i] = make_float2(xi.x - mm.x, xi.y - mm.y);
}

// ---------------- output: stack(real, imag)*norm ----------------
__global__ void output_kernel(const float2* __restrict__ Ximg, const float* __restrict__ sums,
                              float* __restrict__ out){
    int i = blockIdx.x*256 + threadIdx.x;
    float norm = sqrtf(sums[0]/sums[1]);
    float2 v = Ximg[i];
    out[2*i]   = v.x * norm;
    out[2*i+1] = v.y * norm;
}

extern "C" void kernel_launch(void* const* d_in, const int* in_sizes, int n_in,
                              void* d_out, int out_size, void* d_ws, size_t ws_size,
                              hipStream_t stream){
    const float* Xr    = (const float*)d_in[0];
    const float* Xi    = (const float*)d_in[1];
    const float* mask  = (const float*)d_in[2];
    const float* kr    = (const float*)d_in[3];
    const float* ki    = (const float*)d_in[4];
    const float* knots = (const float*)d_in[5];
    const float* alph  = (const float*)d_in[6];
    const float* moms  = (const float*)d_in[7];
    const float* k0    = (const float*)d_in[8];

    float*  ws   = (float*)d_ws;
    float*  sums = ws;                        // 2 floats used (pad to 16)
    float*  Wf   = ws + 16;                   // 8*121*48 = 46464 floats
    float*  Wa   = Wf + 8*121*48;             // 46464 floats
    float2* Xks  = (float2*)(Wa + 8*121*48);
    float2* Ximg = Xks  + NPIX;
    float2* mbuf = Ximg + NPIX;
    float2* tmp  = mbuf + NPIX;
    float2* rg   = tmp  + NPIX;               // 2*NPIX (two partials)
    float2* DX   = rg   + 2*NPIX;             // holds V = DX*act, 75.5 MB

    const float OS = 1.0f/16.0f;              // ortho scale per 1D pass

    hipMemsetAsync(sums, 0, 2*sizeof(float), stream);
    hipMemsetAsync(mbuf, 0, (size_t)NPIX*sizeof(float2), stream);

    repack_kernel<<<(8*121*24 + 255)/256, 256, 0, stream>>>(kr, ki, Wf, Wa);
    reduce_kernel<<<384, 256, 0, stream>>>(Xr, Xi, mask, sums);
    normalize_kernel<<<NPIX/256, 256, 0, stream>>>(Xr, Xi, sums, Xks);

    // X_img = k2i(Xks) * k0   (k2i = centered inverse FFT, dir=+1)
    fft_row_kernel<<<TT*128, 256, 0, stream>>>(Xks, tmp, +1.0f, OS);
    fft_col_kernel<<<TT*(256/CPB), 256, 0, stream>>>(tmp, Ximg, +1.0f, OS, k0);

    for (int l = 0; l < 8; l++){
        conv_fwd_act_kernel<<<dim3(16,16,4), 256, 0, stream>>>(
            Ximg, Wf + (long)l*121*48, knots + (long)l*KN*FC, DX);
        conv_adj_kernel<<<dim3(16,4,2*TT), 256, 0, stream>>>(DX, Wa + (long)l*24*242, rg);
        // data consistency: tmp = i2k(Ximg); tmp = tmp*mask - Xks; tmp = k2i(tmp)
        fft_row_kernel<<<TT*128, 256, 0, stream>>>(Ximg, tmp, -1.0f, OS);
        fft_col_kernel<<<TT*(256/CPB), 256, 0, stream>>>(tmp, tmp, -1.0f, OS, nullptr);
        masksub_kernel<<<NPIX/256, 256, 0, stream>>>(tmp, mask, Xks);
        fft_row_kernel<<<TT*128, 256, 0, stream>>>(tmp, tmp, +1.0f, OS);
        fft_col_kernel<<<TT*(256/CPB), 256, 0, stream>>>(tmp, tmp, +1.0f, OS, nullptr);
        update_kernel<<<NPIX/256, 256, 0, stream>>>(Ximg, mbuf, tmp, rg, alph, moms, l);
    }

    output_kernel<<<NPIX/256, 256, 0, stream>>>(Ximg, sums, (float*)d_out);
}

// Round 4
// 2600.315 us; speedup vs baseline: 1.7184x; 1.7184x over previous
//
#include <hip/hip_runtime.h>
#include <math.h>

#define TT 6
#define FC 24
#define KN 35
#define HW 65536
#define NPIX (TT*HW)   // 393216
#define CPB 16         // columns per block in col-FFT

__device__ inline float2 cmulf(float2 a, float2 b){
    return make_float2(a.x*b.x - a.y*b.y, a.x*b.y + a.y*b.x);
}

// ---------------- reduction: sum|X|^2 and sum(mask) ----------------
__global__ void reduce_kernel(const float* xr, const float* xi, const float* mask, float* sums){
    __shared__ float s1[256], s2[256];
    int tid = threadIdx.x;
    int gid = blockIdx.x*256 + tid;
    float a = 0.f, b = 0.f;
    for (int i = gid; i < NPIX; i += gridDim.x*256) a += xr[i]*xr[i] + xi[i]*xi[i];
    for (int i = gid; i < TT*256; i += gridDim.x*256) b += mask[i];
    s1[tid]=a; s2[tid]=b; __syncthreads();
    for (int off=128; off>0; off>>=1){
        if (tid<off){ s1[tid]+=s1[tid+off]; s2[tid]+=s2[tid+off]; }
        __syncthreads();
    }
    if (tid==0){ atomicAdd(&sums[0], s1[0]); atomicAdd(&sums[1], s2[0]); }
}

// ---------------- normalize: Xks = (xr + i xi)/norm ----------------
__global__ void normalize_kernel(const float* xr, const float* xi, const float* sums, float2* Xks){
    int i = blockIdx.x*256 + threadIdx.x;
    float inv = rsqrtf(sums[0]/sums[1]);
    Xks[i] = make_float2(xr[i]*inv, xi[i]*inv);
}

// ---------------- weight repack: fwd [l][tap][f][ri], adj [l][f][tap-flipped][ri] ----------------
__global__ void repack_kernel(const float* kr, const float* ki, float* Wf, float* Wa){
    int i = blockIdx.x*256 + threadIdx.x;
    if (i >= 8*121*24) return;
    int f   = i % 24;
    int tap = (i/24) % 121;
    int l   = i/(24*121);
    long src = (long)(l*24+f)*121;
    Wf[(((long)l*121+tap)*24+f)*2+0] = kr[src+tap];
    Wf[(((long)l*121+tap)*24+f)*2+1] = ki[src+tap];
    Wa[(((long)l*24+f)*121+tap)*2+0] = kr[src+120-tap];   // spatial flip baked in
    Wa[(((long)l*24+f)*121+tap)*2+1] = ki[src+120-tap];
}

// ---------------- FFT row pass (along W), centered, 2 lines/block ----------------
__global__ void fft_row_kernel(const float2* __restrict__ in, float2* __restrict__ out,
                               float dir, float scale){
    __shared__ float2 lds[2][256];
    __shared__ float2 tw[128];
    int tid = threadIdx.x;
    int line = tid >> 7;
    int j = tid & 127;
    if (tid < 128){
        float s, c;
        sincosf(dir * 6.283185307179586f * (float)tid / 256.0f, &s, &c);
        tw[tid] = make_float2(c, s);
    }
    long gline = (long)blockIdx.x*2 + line;
    const float2* src = in + gline*256;
    {
        float sg = (j & 1) ? -1.f : 1.f;
        float2 a = src[j];
        float2 b = src[j+128];
        lds[line][j]     = make_float2(a.x*sg, a.y*sg);
        lds[line][j+128] = make_float2(b.x*sg, b.y*sg);
    }
    __syncthreads();
    for (int s = 0; s < 8; s++){
        int half = 128 >> s;
        int pos = j & (half-1);
        int grp = j >> (7-s);
        int i0 = (grp << (8-s)) + pos;
        int i1 = i0 + half;
        float2 u = lds[line][i0], v = lds[line][i1];
        float2 w = tw[pos << s];
        lds[line][i0] = make_float2(u.x+v.x, u.y+v.y);
        float2 d = make_float2(u.x-v.x, u.y-v.y);
        lds[line][i1] = cmulf(d, w);
        __syncthreads();
    }
    float2* dst = out + gline*256;
    {
        int k = j;
        float sg = (k & 1) ? -scale : scale;
        float2 v = lds[line][__brev((unsigned)k) >> 24];
        dst[k] = make_float2(v.x*sg, v.y*sg);
        k = j + 128;
        sg = (k & 1) ? -scale : scale;
        v = lds[line][__brev((unsigned)k) >> 24];
        dst[k] = make_float2(v.x*sg, v.y*sg);
    }
}

// ---------------- FFT col pass (along H), centered, 16 cols/block ----------------
__global__ void fft_col_kernel(const float2* __restrict__ in, float2* __restrict__ out,
                               float dir, float scale, const float* k0 /*nullable*/){
    __shared__ float2 lds[256][CPB+1];
    __shared__ float2 tw[128];
    int tid = threadIdx.x;
    if (tid < 128){
        float s, c;
        sincosf(dir * 6.283185307179586f * (float)tid / 256.0f, &s, &c);
        tw[tid] = make_float2(c, s);
    }
    int t  = blockIdx.x / (256/CPB);
    int w0 = (blockIdx.x % (256/CPB)) * CPB;
    const float2* src = in + (long)t*HW;
    float2* dst = out + (long)t*HW;
    int c  = tid & (CPB-1);
    int h0 = tid >> 4;
    for (int i = 0; i < 16; i++){
        int h = h0 + 16*i;
        float2 v = src[h*256 + w0 + c];
        float sg = (h & 1) ? -1.f : 1.f;
        lds[h][c] = make_float2(v.x*sg, v.y*sg);
    }
    __syncthreads();
    int jb = tid >> 4;
    for (int s = 0; s < 8; s++){
        int half = 128 >> s;
        for (int i = 0; i < 8; i++){
            int j = jb + 16*i;
            int pos = j & (half-1);
            int grp = j >> (7-s);
            int i0 = (grp << (8-s)) + pos;
            int i1 = i0 + half;
            float2 u = lds[i0][c], v = lds[i1][c];
            float2 w = tw[pos << s];
            lds[i0][c] = make_float2(u.x+v.x, u.y+v.y);
            float2 d = make_float2(u.x-v.x, u.y-v.y);
            lds[i1][c] = cmulf(d, w);
        }
        __syncthreads();
    }
    float mul = scale;
    if (k0) mul *= *k0;
    for (int i = 0; i < 16; i++){
        int k = h0 + 16*i;
        float2 v = lds[__brev((unsigned)k) >> 24][c];
        float sg = (k & 1) ? -mul : mul;
        dst[k*256 + w0 + c] = make_float2(v.x*sg, v.y*sg);
    }
}

// ---------------- fused forward conv (1->24) + spline act, writes V = DX*act ----
// z = f-group q (0..5): global f in [4q,4q+4). Block does ALL 6 t for a 16x16 tile,
// so the t-sum for the activation is available in registers after the tap loop.
// acc footprint: 4f*6t*2 = 48 floats -> no spill, no launch_bounds min-wave forcing.
__global__ __launch_bounds__(256) void conv_fwd_act_kernel(
        const float2* __restrict__ Ximg, const float* __restrict__ wt,
        const float* __restrict__ knots, float2* __restrict__ V){
    __shared__ float2 xt[6][26][26];
    int q  = blockIdx.z;
    int h0 = blockIdx.y*16, w0 = blockIdx.x*16;
    int tx = threadIdx.x & 15, ty = threadIdx.x >> 4;
    for (int t = 0; t < 6; t++){
        const float2* src = Ximg + (long)t*HW;
        for (int i = threadIdx.x; i < 676; i += 256){
            int yy = i / 26, xx = i - yy*26;
            int gh = h0 + yy - 5, gw = w0 + xx - 5;
            float2 v = make_float2(0.f, 0.f);
            if (gh >= 0 && gh < 256 && gw >= 0 && gw < 256) v = src[gh*256 + gw];
            xt[t][yy][xx] = v;
        }
    }
    __syncthreads();
    float accx[4][6], accy[4][6];   // [f][t]
    #pragma unroll
    for (int f = 0; f < 4; f++)
        #pragma unroll
        for (int t = 0; t < 6; t++){ accx[f][t] = 0.f; accy[f][t] = 0.f; }
    for (int ky = 0; ky < 11; ky++){
        #pragma unroll
        for (int kx = 0; kx < 11; kx++){
            const float* wp = wt + (ky*11 + kx)*48 + q*8;
            float2 a[6];
            #pragma unroll
            for (int t = 0; t < 6; t++) a[t] = xt[t][ty+ky][tx+kx];
            #pragma unroll
            for (int f = 0; f < 4; f++){
                float wr = wp[2*f];
                float wi = wp[2*f+1];
                #pragma unroll
                for (int t = 0; t < 6; t++){
                    accx[f][t] = fmaf(a[t].x, wr, fmaf(-a[t].y, wi, accx[f][t]));
                    accy[f][t] = fmaf(a[t].x, wi, fmaf( a[t].y, wr, accy[f][t]));
                }
            }
        }
    }
    int h = h0 + ty, w = w0 + tx;
    #pragma unroll
    for (int f = 0; f < 4; f++){
        int fg = q*4 + f;
        float s = 0.f;
        #pragma unroll
        for (int t = 0; t < 6; t++) s += accx[f][t]*accx[f][t] + accy[f][t]*accy[f][t];
        float act_in = sqrtf(s) * (1.0f/6.0f);
        float pos = fminf(fmaxf(act_in * 34.0f, 0.0f), 34.0f);
        int i0 = (int)pos; if (i0 > 33) i0 = 33;
        float frac = pos - (float)i0;
        float k0v = knots[i0*24 + fg];
        float k1v = knots[(i0+1)*24 + fg];
        float aout = k0v*(1.0f - frac) + k1v*frac;
        #pragma unroll
        for (int t = 0; t < 6; t++)
            V[((long)(t*24+fg))*HW + h*256 + w] = make_float2(accx[f][t]*aout, accy[f][t]*aout);
    }
}

// ---------------- adjoint complex conv 24->1, 16x32 tile, 2 rows/thread ----------
// Single LDS buffer, all 24 channels sequential; high occupancy does the hiding.
// weights: wa[f*242 + tap*2 + {0,1}] with spatial flip pre-applied
__global__ __launch_bounds__(256) void conv_adj_kernel(const float2* __restrict__ V,
                                                       const float* __restrict__ wa,
                                                       float2* __restrict__ rg){
    __shared__ float2 vt[42][26];
    int t  = blockIdx.z;
    int h0 = blockIdx.y*32, w0 = blockIdx.x*16;
    int tx = threadIdx.x & 15;
    int r0 = (threadIdx.x >> 4) * 2;   // 0..30
    float2 acc[2];
    acc[0] = make_float2(0.f, 0.f);
    acc[1] = make_float2(0.f, 0.f);
    #pragma unroll 1
    for (int f = 0; f < 24; f++){
        const float2* src = V + ((long)(t*24+f))*HW;
        __syncthreads();
        for (int i = threadIdx.x; i < 42*26; i += 256){
            int yy = i / 26, xx = i - yy*26;
            int gh = h0 + yy - 5, gw = w0 + xx - 5;
            float2 v = make_float2(0.f, 0.f);
            if (gh >= 0 && gh < 256 && gw >= 0 && gw < 256) v = src[gh*256 + gw];
            vt[yy][xx] = v;
        }
        __syncthreads();
        const float* wf = wa + f*242;
        #pragma unroll
        for (int sr = 0; sr < 12; sr++){
            float2 v[11];
            #pragma unroll
            for (int kx = 0; kx < 11; kx++) v[kx] = vt[r0+sr][tx+kx];
            #pragma unroll
            for (int rr = 0; rr < 2; rr++){
                int ky = sr - rr;
                if (ky < 0 || ky > 10) continue;   // compile-time resolved
                #pragma unroll
                for (int kx = 0; kx < 11; kx++){
                    float wr = wf[(ky*11+kx)*2+0];
                    float wi = wf[(ky*11+kx)*2+1];
                    acc[rr].x = fmaf(v[kx].x, wr, fmaf( v[kx].y, wi, acc[rr].x));
                    acc[rr].y = fmaf(v[kx].y, wr, fmaf(-v[kx].x, wi, acc[rr].y));
                }
            }
        }
    }
    float2* out = rg + (long)t*HW;
    out[(h0 + r0    )*256 + (w0 + tx)] = acc[0];
    out[(h0 + r0 + 1)*256 + (w0 + tx)] = acc[1];
}

// ---------------- k-space mask + subtract ----------------
__global__ void masksub_kernel(float2* __restrict__ tmp, const float* __restrict__ mask,
                               const float2* __restrict__ Xks){
    int i = blockIdx.x*256 + threadIdx.x;
    int t = i >> 16;
    int w = i & 255;
    float mv = mask[t*256 + w];
    float2 v = tmp[i], x = Xks[i];
    tmp[i] = make_float2(v.x*mv - x.x, v.y*mv - x.y);
}

// ---------------- momentum update ----------------
__global__ void update_kernel(float2* __restrict__ Ximg, float2* __restrict__ m,
                              const float2* __restrict__ dg, const float2* __restrict__ rg,
                              const float* __restrict__ alphas, const float* __restrict__ moms, int l){
    int i = blockIdx.x*256 + threadIdx.x;
    float a  = alphas[l];
    float mu = moms[l];
    float2 r0 = rg[i];
    float2 g  = make_float2(fmaf(a, dg[i].x, r0.x), fmaf(a, dg[i].y, r0.y));
    float2 mm = make_float2(fmaf(mu, m[i].x, g.x), fmaf(mu, m[i].y, g.y));
    m[i] = mm;
    float2 xi = Ximg[i];
    Ximg[i] = make_float2(xi.x - mm.x, xi.y - mm.y);
}

// ---------------- output: stack(real, imag)*norm ----------------
__global__ void output_kernel(const float2* __restrict__ Ximg, const float* __restrict__ sums,
                              float* __restrict__ out){
    int i = blockIdx.x*256 + threadIdx.x;
    float norm = sqrtf(sums[0]/sums[1]);
    float2 v = Ximg[i];
    out[2*i]   = v.x * norm;
    out[2*i+1] = v.y * norm;
}

extern "C" void kernel_launch(void* const* d_in, const int* in_sizes, int n_in,
                              void* d_out, int out_size, void* d_ws, size_t ws_size,
                              hipStream_t stream){
    const float* Xr    = (const float*)d_in[0];
    const float* Xi    = (const float*)d_in[1];
    const float* mask  = (const float*)d_in[2];
    const float* kr    = (const float*)d_in[3];
    const float* ki    = (const float*)d_in[4];
    const float* knots = (const float*)d_in[5];
    const float* alph  = (const float*)d_in[6];
    const float* moms  = (const float*)d_in[7];
    const float* k0    = (const float*)d_in[8];

    float*  ws   = (float*)d_ws;
    float*  sums = ws;                        // 2 floats used (pad to 16)
    float*  Wf   = ws + 16;                   // 8*121*48 = 46464 floats
    float*  Wa   = Wf + 8*121*48;             // 46464 floats
    float2* Xks  = (float2*)(Wa + 8*121*48);
    float2* Ximg = Xks  + NPIX;
    float2* mbuf = Ximg + NPIX;
    float2* tmp  = mbuf + NPIX;
    float2* rg   = tmp  + NPIX;
    float2* DX   = rg   + NPIX;               // holds V = DX*act, 75.5 MB

    const float OS = 1.0f/16.0f;              // ortho scale per 1D pass

    hipMemsetAsync(sums, 0, 2*sizeof(float), stream);
    hipMemsetAsync(mbuf, 0, (size_t)NPIX*sizeof(float2), stream);

    repack_kernel<<<(8*121*24 + 255)/256, 256, 0, stream>>>(kr, ki, Wf, Wa);
    reduce_kernel<<<384, 256, 0, stream>>>(Xr, Xi, mask, sums);
    normalize_kernel<<<NPIX/256, 256, 0, stream>>>(Xr, Xi, sums, Xks);

    // X_img = k2i(Xks) * k0   (k2i = centered inverse FFT, dir=+1)
    fft_row_kernel<<<TT*128, 256, 0, stream>>>(Xks, tmp, +1.0f, OS);
    fft_col_kernel<<<TT*(256/CPB), 256, 0, stream>>>(tmp, Ximg, +1.0f, OS, k0);

    for (int l = 0; l < 8; l++){
        conv_fwd_act_kernel<<<dim3(16,16,6), 256, 0, stream>>>(
            Ximg, Wf + (long)l*121*48, knots + (long)l*KN*FC, DX);
        conv_adj_kernel<<<dim3(16,8,TT), 256, 0, stream>>>(DX, Wa + (long)l*24*242, rg);
        // data consistency: tmp = i2k(Ximg); tmp = tmp*mask - Xks; tmp = k2i(tmp)
        fft_row_kernel<<<TT*128, 256, 0, stream>>>(Ximg, tmp, -1.0f, OS);
        fft_col_kernel<<<TT*(256/CPB), 256, 0, stream>>>(tmp, tmp, -1.0f, OS, nullptr);
        masksub_kernel<<<NPIX/256, 256, 0, stream>>>(tmp, mask, Xks);
        fft_row_kernel<<<TT*128, 256, 0, stream>>>(tmp, tmp, +1.0f, OS);
        fft_col_kernel<<<TT*(256/CPB), 256, 0, stream>>>(tmp, tmp, +1.0f, OS, nullptr);
        update_kernel<<<NPIX/256, 256, 0, stream>>>(Ximg, mbuf, tmp, rg, alph, moms, l);
    }

    output_kernel<<<NPIX/256, 256, 0, stream>>>(Ximg, sums, (float*)d_out);
}

// Round 5
// 2189.814 us; speedup vs baseline: 2.0405x; 1.1875x over previous
//
#include <hip/hip_runtime.h>
#include <math.h>

#define TT 6
#define FC 24
#define KN 35
#define HW 65536
#define NPIX (TT*HW)   // 393216
#define CPB 16         // columns per block in col-FFT

// padded V geometry (float2 units): 5-halo on all sides, stride rounded for 16B chunks
#define VSTRIDE 272
#define VROWS   266
#define VPLANE  (VROWS*VSTRIDE)          // 72352 float2 per (t,f) plane
#define VIOFF   (5*VSTRIDE + 5)          // interior origin
#define NPLANES (TT*FC)                  // 144

__device__ inline float2 cmulf(float2 a, float2 b){
    return make_float2(a.x*b.x - a.y*b.y, a.x*b.y + a.y*b.x);
}

__device__ inline void gl_lds16(const float2* g, void* l){
    __builtin_amdgcn_global_load_lds((const __attribute__((address_space(1))) unsigned int*)g,
                                     (__attribute__((address_space(3))) unsigned int*)l,
                                     16, 0, 0);
}

// ---------------- reduction: sum|X|^2 and sum(mask) ----------------
__global__ void reduce_kernel(const float* xr, const float* xi, const float* mask, float* sums){
    __shared__ float s1[256], s2[256];
    int tid = threadIdx.x;
    int gid = blockIdx.x*256 + tid;
    float a = 0.f, b = 0.f;
    for (int i = gid; i < NPIX; i += gridDim.x*256) a += xr[i]*xr[i] + xi[i]*xi[i];
    for (int i = gid; i < TT*256; i += gridDim.x*256) b += mask[i];
    s1[tid]=a; s2[tid]=b; __syncthreads();
    for (int off=128; off>0; off>>=1){
        if (tid<off){ s1[tid]+=s1[tid+off]; s2[tid]+=s2[tid+off]; }
        __syncthreads();
    }
    if (tid==0){ atomicAdd(&sums[0], s1[0]); atomicAdd(&sums[1], s2[0]); }
}

// ---------------- normalize: Xks = (xr + i xi)/norm ----------------
__global__ void normalize_kernel(const float* xr, const float* xi, const float* sums, float2* Xks){
    int i = blockIdx.x*256 + threadIdx.x;
    float inv = rsqrtf(sums[0]/sums[1]);
    Xks[i] = make_float2(xr[i]*inv, xi[i]*inv);
}

// ---------------- weight repack: fwd [l][tap][f][ri], adj [l][f][tap-flipped][ri] ----------------
__global__ void repack_kernel(const float* kr, const float* ki, float* Wf, float* Wa){
    int i = blockIdx.x*256 + threadIdx.x;
    if (i >= 8*121*24) return;
    int f   = i % 24;
    int tap = (i/24) % 121;
    int l   = i/(24*121);
    long src = (long)(l*24+f)*121;
    Wf[(((long)l*121+tap)*24+f)*2+0] = kr[src+tap];
    Wf[(((long)l*121+tap)*24+f)*2+1] = ki[src+tap];
    Wa[(((long)l*24+f)*121+tap)*2+0] = kr[src+120-tap];   // spatial flip baked in
    Wa[(((long)l*24+f)*121+tap)*2+1] = ki[src+120-tap];
}

// ---------------- FFT row pass (init only), centered, 2 lines/block ----------------
__global__ void fft_row_kernel(const float2* __restrict__ in, float2* __restrict__ out,
                               float dir, float scale){
    __shared__ float2 lds[2][256];
    __shared__ float2 tw[128];
    int tid = threadIdx.x;
    int line = tid >> 7;
    int j = tid & 127;
    if (tid < 128){
        float s, c;
        sincosf(dir * 6.283185307179586f * (float)tid / 256.0f, &s, &c);
        tw[tid] = make_float2(c, s);
    }
    long gline = (long)blockIdx.x*2 + line;
    const float2* src = in + gline*256;
    {
        float sg = (j & 1) ? -1.f : 1.f;
        float2 a = src[j];
        float2 b = src[j+128];
        lds[line][j]     = make_float2(a.x*sg, a.y*sg);
        lds[line][j+128] = make_float2(b.x*sg, b.y*sg);
    }
    __syncthreads();
    for (int s = 0; s < 8; s++){
        int half = 128 >> s;
        int pos = j & (half-1);
        int grp = j >> (7-s);
        int i0 = (grp << (8-s)) + pos;
        int i1 = i0 + half;
        float2 u = lds[line][i0], v = lds[line][i1];
        float2 w = tw[pos << s];
        lds[line][i0] = make_float2(u.x+v.x, u.y+v.y);
        float2 d = make_float2(u.x-v.x, u.y-v.y);
        lds[line][i1] = cmulf(d, w);
        __syncthreads();
    }
    float2* dst = out + gline*256;
    {
        int k = j;
        float sg = (k & 1) ? -scale : scale;
        float2 v = lds[line][__brev((unsigned)k) >> 24];
        dst[k] = make_float2(v.x*sg, v.y*sg);
        k = j + 128;
        sg = (k & 1) ? -scale : scale;
        v = lds[line][__brev((unsigned)k) >> 24];
        dst[k] = make_float2(v.x*sg, v.y*sg);
    }
}

// ---------------- FFT col pass (init only): writes Ximg (*k0) and G (no k0) ------
__global__ void fft_col_kernel(const float2* __restrict__ in, float2* __restrict__ Ximg,
                               float2* __restrict__ G, float dir, float scale, const float* k0){
    __shared__ float2 lds[256][CPB+1];
    __shared__ float2 tw[128];
    int tid = threadIdx.x;
    if (tid < 128){
        float s, c;
        sincosf(dir * 6.283185307179586f * (float)tid / 256.0f, &s, &c);
        tw[tid] = make_float2(c, s);
    }
    int t  = blockIdx.x / (256/CPB);
    int w0 = (blockIdx.x % (256/CPB)) * CPB;
    const float2* src = in + (long)t*HW;
    int c  = tid & (CPB-1);
    int h0 = tid >> 4;
    for (int i = 0; i < 16; i++){
        int h = h0 + 16*i;
        float2 v = src[h*256 + w0 + c];
        float sg = (h & 1) ? -1.f : 1.f;
        lds[h][c] = make_float2(v.x*sg, v.y*sg);
    }
    __syncthreads();
    int jb = tid >> 4;
    for (int s = 0; s < 8; s++){
        int half = 128 >> s;
        for (int i = 0; i < 8; i++){
            int j = jb + 16*i;
            int pos = j & (half-1);
            int grp = j >> (7-s);
            int i0 = (grp << (8-s)) + pos;
            int i1 = i0 + half;
            float2 u = lds[i0][c], v = lds[i1][c];
            float2 w = tw[pos << s];
            lds[i0][c] = make_float2(u.x+v.x, u.y+v.y);
            float2 d = make_float2(u.x-v.x, u.y-v.y);
            lds[i1][c] = cmulf(d, w);
        }
        __syncthreads();
    }
    float kk = *k0;
    for (int i = 0; i < 16; i++){
        int k = h0 + 16*i;
        float2 v = lds[__brev((unsigned)k) >> 24][c];
        float sg = (k & 1) ? -scale : scale;
        float2 g = make_float2(v.x*sg, v.y*sg);
        long idx = (long)t*HW + k*256 + w0 + c;
        G[idx]    = g;
        Ximg[idx] = make_float2(g.x*kk, g.y*kk);
    }
}

// ---------------- fused forward conv (1->24) + spline act, writes V (padded) ----
__global__ __launch_bounds__(256) void conv_fwd_act_kernel(
        const float2* __restrict__ Ximg, const float* __restrict__ wt,
        const float* __restrict__ knots, float2* __restrict__ V){
    __shared__ float2 xt[6][26][26];
    int q  = blockIdx.z;
    int h0 = blockIdx.y*16, w0 = blockIdx.x*16;
    int tx = threadIdx.x & 15, ty = threadIdx.x >> 4;
    for (int t = 0; t < 6; t++){
        const float2* src = Ximg + (long)t*HW;
        for (int i = threadIdx.x; i < 676; i += 256){
            int yy = i / 26, xx = i - yy*26;
            int gh = h0 + yy - 5, gw = w0 + xx - 5;
            float2 v = make_float2(0.f, 0.f);
            if (gh >= 0 && gh < 256 && gw >= 0 && gw < 256) v = src[gh*256 + gw];
            xt[t][yy][xx] = v;
        }
    }
    __syncthreads();
    float accx[4][6], accy[4][6];   // [f][t]
    #pragma unroll
    for (int f = 0; f < 4; f++)
        #pragma unroll
        for (int t = 0; t < 6; t++){ accx[f][t] = 0.f; accy[f][t] = 0.f; }
    for (int ky = 0; ky < 11; ky++){
        #pragma unroll
        for (int kx = 0; kx < 11; kx++){
            const float* wp = wt + (ky*11 + kx)*48 + q*8;
            float2 a[6];
            #pragma unroll
            for (int t = 0; t < 6; t++) a[t] = xt[t][ty+ky][tx+kx];
            #pragma unroll
            for (int f = 0; f < 4; f++){
                float wr = wp[2*f];
                float wi = wp[2*f+1];
                #pragma unroll
                for (int t = 0; t < 6; t++){
                    accx[f][t] = fmaf(a[t].x, wr, fmaf(-a[t].y, wi, accx[f][t]));
                    accy[f][t] = fmaf(a[t].x, wi, fmaf( a[t].y, wr, accy[f][t]));
                }
            }
        }
    }
    int h = h0 + ty, w = w0 + tx;
    #pragma unroll
    for (int f = 0; f < 4; f++){
        int fg = q*4 + f;
        float s = 0.f;
        #pragma unroll
        for (int t = 0; t < 6; t++) s += accx[f][t]*accx[f][t] + accy[f][t]*accy[f][t];
        float act_in = sqrtf(s) * (1.0f/6.0f);
        float pos = fminf(fmaxf(act_in * 34.0f, 0.0f), 34.0f);
        int i0 = (int)pos; if (i0 > 33) i0 = 33;
        float frac = pos - (float)i0;
        float k0v = knots[i0*24 + fg];
        float k1v = knots[(i0+1)*24 + fg];
        float aout = k0v*(1.0f - frac) + k1v*frac;
        #pragma unroll
        for (int t = 0; t < 6; t++)
            V[(long)(t*24+fg)*VPLANE + VIOFF + h*VSTRIDE + w] =
                make_float2(accx[f][t]*aout, accy[f][t]*aout);
    }
}

// ---------------- adjoint conv 24->1: async LDS double-buffer over channels ------
// tile 16x32, 2 rows/thread; stage = 42 rows x 13 chunks(16B) = 546 chunks from padded V.
__global__ __launch_bounds__(256) void conv_adj_kernel(const float2* __restrict__ V,
                                                       const float* __restrict__ wa,
                                                       float2* __restrict__ rg){
    __shared__ float2 vt[2][42][26];   // 2 x 8736 B
    int t  = blockIdx.z;
    int h0 = blockIdx.y*32, w0 = blockIdx.x*16;
    int tx = threadIdx.x & 15;
    int r0 = (threadIdx.x >> 4) * 2;   // 0..30
    int wv = threadIdx.x >> 6, ln = threadIdx.x & 63;

    // per-lane global srcs for 3 issue rounds (chunk s = r*256 + wv*64 + ln)
    const float2* gsrc[3];
    unsigned lofs[3];
    bool act[3];
    {
        const float2* plane0 = V + (long)(t*24)*VPLANE;   // channel 0 of this t
        #pragma unroll
        for (int r = 0; r < 3; r++){
            int s = r*256 + wv*64 + ln;
            act[r] = (s < 546);
            int row = s / 13;
            int col = s - row*13;
            gsrc[r] = plane0 + (long)(h0 + row)*VSTRIDE + w0 + col*2;  // halo: origin already -5,-5 via VIOFF-less base? no:
            lofs[r] = (unsigned)(r*256 + wv*64)*16u;
        }
    }
    // NOTE: gsrc above indexes from plane start; plane start = (row -5, col -5) interior
    // origin offset handled here: interior (h0-5+row, w0-5+col*2) == plane_base + (h0+row)*VSTRIDE + (w0 + col*2)
    // because plane_base points at padded (0,0) and interior starts at VIOFF = (5,5).

    {   // prologue: stage channel 0 into buf 0
        #pragma unroll
        for (int r = 0; r < 3; r++)
            if (act[r]) gl_lds16(gsrc[r], (char*)(&vt[0][0][0]) + lofs[r]);
    }
    float2 acc0 = make_float2(0.f,0.f), acc1 = make_float2(0.f,0.f);

    #pragma unroll 1
    for (int f = 0; f < 24; f++){
        int buf = f & 1;
        __syncthreads();   // drains own vmcnt -> vt[buf] complete; prev readers of vt[buf^1] done
        if (f + 1 < 24){   // async-stage next channel into the other buffer
            #pragma unroll
            for (int r = 0; r < 3; r++){
                if (act[r]) gl_lds16(gsrc[r] + (long)VPLANE, (char*)(&vt[buf^1][0][0]) + lofs[r]);
                gsrc[r] += VPLANE;
            }
        }
        const float* wf = wa + f*242;
        #pragma unroll
        for (int sr = 0; sr < 12; sr++){
            float2 v[11];
            #pragma unroll
            for (int kx = 0; kx < 11; kx++) v[kx] = vt[buf][r0+sr][tx+kx];
            #pragma unroll
            for (int rr = 0; rr < 2; rr++){
                int ky = sr - rr;
                if (ky < 0 || ky > 10) continue;   // compile-time resolved
                float2* ac = rr ? &acc1 : &acc0;
                #pragma unroll
                for (int kx = 0; kx < 11; kx++){
                    float wr = wf[(ky*11+kx)*2+0];
                    float wi = wf[(ky*11+kx)*2+1];
                    ac->x = fmaf(v[kx].x, wr, fmaf( v[kx].y, wi, ac->x));
                    ac->y = fmaf(v[kx].y, wr, fmaf(-v[kx].x, wi, ac->y));
                }
            }
        }
    }
    float2* out = rg + (long)t*HW;
    out[(h0 + r0    )*256 + (w0 + tx)] = acc0;
    out[(h0 + r0 + 1)*256 + (w0 + tx)] = acc1;
}

// ---------------- fused data-consistency + momentum update --------------------
// dg = R+( mask/256 * R-(Ximg) ) - G ;  m = mu*m + alpha*dg + rg ; Ximg -= m
// (col FFTs cancel: mask is constant along H; G = k2i(Xks) precomputed)
__global__ void dc_update_kernel(float2* __restrict__ Ximg, float2* __restrict__ m,
                                 const float2* __restrict__ rg, const float2* __restrict__ G,
                                 const float* __restrict__ mask,
                                 const float* __restrict__ alphas, const float* __restrict__ moms,
                                 int l){
    __shared__ float2 lds[2][256];
    __shared__ float2 tw[128];    // e^{+i 2pi k/256}
    int tid = threadIdx.x;
    int line = tid >> 7;
    int j = tid & 127;
    if (tid < 128){
        float s, c;
        sincosf(6.283185307179586f * (float)tid / 256.0f, &s, &c);
        tw[tid] = make_float2(c, s);
    }
    long gl = (long)blockIdx.x*2 + line;   // = t*256 + h
    int t = (int)(gl >> 8);
    float2* src = Ximg + gl*256;
    float2 xo0, xo1;
    {   // load with (-1)^n
        float sg = (j & 1) ? -1.f : 1.f;
        xo0 = src[j]; xo1 = src[j+128];
        lds[line][j]     = make_float2(xo0.x*sg, xo0.y*sg);
        lds[line][j+128] = make_float2(xo1.x*sg, xo1.y*sg);
    }
    __syncthreads();
    // FFT1: DIF, dir = -1 (conj tw), natural in -> bit-reversed out
    for (int s = 0; s < 8; s++){
        int half = 128 >> s;
        int pos = j & (half-1);
        int grp = j >> (7-s);
        int i0 = (grp << (8-s)) + pos;
        int i1 = i0 + half;
        float2 u = lds[line][i0], v = lds[line][i1];
        float2 w = tw[pos << s]; w.y = -w.y;           // conj -> dir -1
        lds[line][i0] = make_float2(u.x+v.x, u.y+v.y);
        float2 d = make_float2(u.x-v.x, u.y-v.y);
        lds[line][i1] = cmulf(d, w);
        __syncthreads();
    }
    // middle: multiply by mask(natural k)/256; (-1)^k signs of FFT1-post/FFT2-pre cancel
    {
        int k1 = __brev((unsigned)j) >> 24;
        int k2 = __brev((unsigned)(j+128)) >> 24;
        float mv1 = mask[t*256 + k1] * (1.0f/256.0f);
        float mv2 = mask[t*256 + k2] * (1.0f/256.0f);
        float2 a = lds[line][j], b = lds[line][j+128];
        lds[line][j]     = make_float2(a.x*mv1, a.y*mv1);
        lds[line][j+128] = make_float2(b.x*mv2, b.y*mv2);
    }
    __syncthreads();
    // FFT2: DIT, dir = +1, bit-reversed in -> natural out
    for (int s = 0; s < 8; s++){
        int m2 = 1 << s;
        int pos = j & (m2-1);
        int grp = j >> s;
        int i0 = (grp << (s+1)) + pos;
        int i1 = i0 + m2;
        float2 u = lds[line][i0];
        float2 v = cmulf(lds[line][i1], tw[pos << (7-s)]);
        lds[line][i0] = make_float2(u.x+v.x, u.y+v.y);
        lds[line][i1] = make_float2(u.x-v.x, u.y-v.y);
        __syncthreads();
    }
    // epilogue: (-1)^k, then momentum update on both elements
    float a  = alphas[l];
    float mu = moms[l];
    float sg = (j & 1) ? -1.f : 1.f;
    #pragma unroll
    for (int half = 0; half < 2; half++){
        int k = j + half*128;
        long idx = gl*256 + k;
        float2 d = lds[line][k];
        d = make_float2(d.x*sg, d.y*sg);
        float2 g = G[idx];
        float2 r = rg[idx];
        float2 grad = make_float2(fmaf(a, d.x - g.x, r.x), fmaf(a, d.y - g.y, r.y));
        float2 mv = m[idx];
        float2 mm = make_float2(fmaf(mu, mv.x, grad.x), fmaf(mu, mv.y, grad.y));
        m[idx] = mm;
        float2 xo = half ? xo1 : xo0;
        Ximg[idx] = make_float2(xo.x - mm.x, xo.y - mm.y);
    }
}

// ---------------- output: stack(real, imag)*norm ----------------
__global__ void output_kernel(const float2* __restrict__ Ximg, const float* __restrict__ sums,
                              float* __restrict__ out){
    int i = blockIdx.x*256 + threadIdx.x;
    float norm = sqrtf(sums[0]/sums[1]);
    float2 v = Ximg[i];
    out[2*i]   = v.x * norm;
    out[2*i+1] = v.y * norm;
}

extern "C" void kernel_launch(void* const* d_in, const int* in_sizes, int n_in,
                              void* d_out, int out_size, void* d_ws, size_t ws_size,
                              hipStream_t stream){
    const float* Xr    = (const float*)d_in[0];
    const float* Xi    = (const float*)d_in[1];
    const float* mask  = (const float*)d_in[2];
    const float* kr    = (const float*)d_in[3];
    const float* ki    = (const float*)d_in[4];
    const float* knots = (const float*)d_in[5];
    const float* alph  = (const float*)d_in[6];
    const float* moms  = (const float*)d_in[7];
    const float* k0    = (const float*)d_in[8];

    float*  ws   = (float*)d_ws;
    float*  sums = ws;                        // 2 floats used (pad to 16)
    float*  Wf   = ws + 16;                   // 8*121*48 = 46464 floats
    float*  Wa   = Wf + 8*121*48;             // 46464 floats
    float2* Xks  = (float2*)(Wa + 8*121*48);
    float2* Ximg = Xks  + NPIX;
    float2* mbuf = Ximg + NPIX;
    float2* tmp  = mbuf + NPIX;
    float2* rg   = tmp  + NPIX;
    float2* G    = rg   + NPIX;
    float2* V    = G    + NPIX;               // padded: 144 * 72352 float2 = 83.3 MB

    const float OS = 1.0f/16.0f;              // ortho scale per 1D pass

    hipMemsetAsync(sums, 0, 2*sizeof(float), stream);
    hipMemsetAsync(mbuf, 0, (size_t)NPIX*sizeof(float2), stream);
    hipMemsetAsync(V,    0, (size_t)NPLANES*VPLANE*sizeof(float2), stream);  // zero halos

    repack_kernel<<<(8*121*24 + 255)/256, 256, 0, stream>>>(kr, ki, Wf, Wa);
    reduce_kernel<<<384, 256, 0, stream>>>(Xr, Xi, mask, sums);
    normalize_kernel<<<NPIX/256, 256, 0, stream>>>(Xr, Xi, sums, Xks);

    // init: Ximg = k2i(Xks)*k0 ; G = k2i(Xks)
    fft_row_kernel<<<TT*128, 256, 0, stream>>>(Xks, tmp, +1.0f, OS);
    fft_col_kernel<<<TT*(256/CPB), 256, 0, stream>>>(tmp, Ximg, G, +1.0f, OS, k0);

    for (int l = 0; l < 8; l++){
        conv_fwd_act_kernel<<<dim3(16,16,6), 256, 0, stream>>>(
            Ximg, Wf + (long)l*121*48, knots + (long)l*KN*FC, V);
        conv_adj_kernel<<<dim3(16,8,TT), 256, 0, stream>>>(V, Wa + (long)l*24*242, rg);
        dc_update_kernel<<<TT*128, 256, 0, stream>>>(Ximg, mbuf, rg, G, mask, alph, moms, l);
    }

    output_kernel<<<NPIX/256, 256, 0, stream>>>(Ximg, sums, (float*)d_out);
}

// Round 6
// 1951.945 us; speedup vs baseline: 2.2892x; 1.1219x over previous
//
#include <hip/hip_runtime.h>
#include <math.h>

#define TT 6
#define FC 24
#define KN 35
#define HW 65536
#define NPIX (TT*HW)   // 393216
#define CPB 16         // columns per block in col-FFT

// padded plane geometry (float2 units): 5-halo on all sides, stride rounded for 16B chunks
#define VSTRIDE 272
#define VROWS   266
#define VPLANE  (VROWS*VSTRIDE)          // 72352 float2 per plane
#define VIOFF   (5*VSTRIDE + 5)          // interior origin
#define NPLANES (TT*FC)                  // 144

__device__ inline float2 cmulf(float2 a, float2 b){
    return make_float2(a.x*b.x - a.y*b.y, a.x*b.y + a.y*b.x);
}

__device__ inline void gl_lds16(const float2* g, void* l){
    __builtin_amdgcn_global_load_lds((const __attribute__((address_space(1))) unsigned int*)g,
                                     (__attribute__((address_space(3))) unsigned int*)l,
                                     16, 0, 0);
}

// ---------------- reduction: sum|X|^2 and sum(mask) ----------------
__global__ void reduce_kernel(const float* xr, const float* xi, const float* mask, float* sums){
    __shared__ float s1[256], s2[256];
    int tid = threadIdx.x;
    int gid = blockIdx.x*256 + tid;
    float a = 0.f, b = 0.f;
    for (int i = gid; i < NPIX; i += gridDim.x*256) a += xr[i]*xr[i] + xi[i]*xi[i];
    for (int i = gid; i < TT*256; i += gridDim.x*256) b += mask[i];
    s1[tid]=a; s2[tid]=b; __syncthreads();
    for (int off=128; off>0; off>>=1){
        if (tid<off){ s1[tid]+=s1[tid+off]; s2[tid]+=s2[tid+off]; }
        __syncthreads();
    }
    if (tid==0){ atomicAdd(&sums[0], s1[0]); atomicAdd(&sums[1], s2[0]); }
}

// ---------------- normalize: Xks = (xr + i xi)/norm ----------------
__global__ void normalize_kernel(const float* xr, const float* xi, const float* sums, float2* Xks){
    int i = blockIdx.x*256 + threadIdx.x;
    float inv = rsqrtf(sums[0]/sums[1]);
    Xks[i] = make_float2(xr[i]*inv, xi[i]*inv);
}

// ---------------- weight repack: fwd [l][tap][f][ri], adj [l][f][tap-flipped][ri] ----------------
__global__ void repack_kernel(const float* kr, const float* ki, float* Wf, float* Wa){
    int i = blockIdx.x*256 + threadIdx.x;
    if (i >= 8*121*24) return;
    int f   = i % 24;
    int tap = (i/24) % 121;
    int l   = i/(24*121);
    long src = (long)(l*24+f)*121;
    Wf[(((long)l*121+tap)*24+f)*2+0] = kr[src+tap];
    Wf[(((long)l*121+tap)*24+f)*2+1] = ki[src+tap];
    Wa[(((long)l*24+f)*121+tap)*2+0] = kr[src+120-tap];   // spatial flip baked in
    Wa[(((long)l*24+f)*121+tap)*2+1] = ki[src+120-tap];
}

// ---------------- FFT row pass (init only), centered, 2 lines/block ----------------
__global__ void fft_row_kernel(const float2* __restrict__ in, float2* __restrict__ out,
                               float dir, float scale){
    __shared__ float2 lds[2][256];
    __shared__ float2 tw[128];
    int tid = threadIdx.x;
    int line = tid >> 7;
    int j = tid & 127;
    if (tid < 128){
        float s, c;
        sincosf(dir * 6.283185307179586f * (float)tid / 256.0f, &s, &c);
        tw[tid] = make_float2(c, s);
    }
    long gline = (long)blockIdx.x*2 + line;
    const float2* src = in + gline*256;
    {
        float sg = (j & 1) ? -1.f : 1.f;
        float2 a = src[j];
        float2 b = src[j+128];
        lds[line][j]     = make_float2(a.x*sg, a.y*sg);
        lds[line][j+128] = make_float2(b.x*sg, b.y*sg);
    }
    __syncthreads();
    for (int s = 0; s < 8; s++){
        int half = 128 >> s;
        int pos = j & (half-1);
        int grp = j >> (7-s);
        int i0 = (grp << (8-s)) + pos;
        int i1 = i0 + half;
        float2 u = lds[line][i0], v = lds[line][i1];
        float2 w = tw[pos << s];
        lds[line][i0] = make_float2(u.x+v.x, u.y+v.y);
        float2 d = make_float2(u.x-v.x, u.y-v.y);
        lds[line][i1] = cmulf(d, w);
        __syncthreads();
    }
    float2* dst = out + gline*256;
    {
        int k = j;
        float sg = (k & 1) ? -scale : scale;
        float2 v = lds[line][__brev((unsigned)k) >> 24];
        dst[k] = make_float2(v.x*sg, v.y*sg);
        k = j + 128;
        sg = (k & 1) ? -scale : scale;
        v = lds[line][__brev((unsigned)k) >> 24];
        dst[k] = make_float2(v.x*sg, v.y*sg);
    }
}

// ---------------- FFT col pass (init only): writes Xpad (*k0, padded) and G ------
__global__ void fft_col_kernel(const float2* __restrict__ in, float2* __restrict__ Xpad,
                               float2* __restrict__ G, float dir, float scale, const float* k0){
    __shared__ float2 lds[256][CPB+1];
    __shared__ float2 tw[128];
    int tid = threadIdx.x;
    if (tid < 128){
        float s, c;
        sincosf(dir * 6.283185307179586f * (float)tid / 256.0f, &s, &c);
        tw[tid] = make_float2(c, s);
    }
    int t  = blockIdx.x / (256/CPB);
    int w0 = (blockIdx.x % (256/CPB)) * CPB;
    const float2* src = in + (long)t*HW;
    int c  = tid & (CPB-1);
    int h0 = tid >> 4;
    for (int i = 0; i < 16; i++){
        int h = h0 + 16*i;
        float2 v = src[h*256 + w0 + c];
        float sg = (h & 1) ? -1.f : 1.f;
        lds[h][c] = make_float2(v.x*sg, v.y*sg);
    }
    __syncthreads();
    int jb = tid >> 4;
    for (int s = 0; s < 8; s++){
        int half = 128 >> s;
        for (int i = 0; i < 8; i++){
            int j = jb + 16*i;
            int pos = j & (half-1);
            int grp = j >> (7-s);
            int i0 = (grp << (8-s)) + pos;
            int i1 = i0 + half;
            float2 u = lds[i0][c], v = lds[i1][c];
            float2 w = tw[pos << s];
            lds[i0][c] = make_float2(u.x+v.x, u.y+v.y);
            float2 d = make_float2(u.x-v.x, u.y-v.y);
            lds[i1][c] = cmulf(d, w);
        }
        __syncthreads();
    }
    float kk = *k0;
    for (int i = 0; i < 16; i++){
        int k = h0 + 16*i;
        float2 v = lds[__brev((unsigned)k) >> 24][c];
        float sg = (k & 1) ? -scale : scale;
        float2 g = make_float2(v.x*sg, v.y*sg);
        G[(long)t*HW + k*256 + w0 + c] = g;
        Xpad[(long)t*VPLANE + VIOFF + k*VSTRIDE + w0 + c] = make_float2(g.x*kk, g.y*kk);
    }
}

// ---------------- fused forward conv (1->24) + spline act: async staging ---------
// q = blockIdx.z (0..5): f in [4q,4q+4). Stage all 6 t-planes of the 26x26 tile via DMA.
__global__ __launch_bounds__(256) void conv_fwd_act_kernel(
        const float2* __restrict__ Xpad, const float* __restrict__ wt,
        const float* __restrict__ knots, float2* __restrict__ V){
    __shared__ __align__(16) float2 xt[6][26][26];   // 338 chunks/plane, 2028 total
    int q  = blockIdx.z;
    int h0 = blockIdx.y*16, w0 = blockIdx.x*16;
    int tx = threadIdx.x & 15, ty = threadIdx.x >> 4;
    int wv = threadIdx.x >> 6, ln = threadIdx.x & 63;
    {   // DMA stage: chunk s -> (t = s/338, row = (s%338)/13, colpair = (s%338)%13)
        #pragma unroll
        for (int r = 0; r < 8; r++){
            int s = r*256 + wv*64 + ln;
            if (s < 2028){
                int t = s / 338, rem = s - t*338;
                int row = rem / 13, col = rem - row*13;
                const float2* g = Xpad + (long)t*VPLANE + (long)(h0 + row)*VSTRIDE + w0 + col*2;
                gl_lds16(g, (char*)(&xt[0][0][0]) + (unsigned)(r*256 + wv*64)*16u);
            }
        }
    }
    __syncthreads();
    float accx[4][6], accy[4][6];   // [f][t]
    #pragma unroll
    for (int f = 0; f < 4; f++)
        #pragma unroll
        for (int t = 0; t < 6; t++){ accx[f][t] = 0.f; accy[f][t] = 0.f; }
    for (int ky = 0; ky < 11; ky++){
        #pragma unroll
        for (int kx = 0; kx < 11; kx++){
            const float* wp = wt + (ky*11 + kx)*48 + q*8;
            float2 a[6];
            #pragma unroll
            for (int t = 0; t < 6; t++) a[t] = xt[t][ty+ky][tx+kx];
            #pragma unroll
            for (int f = 0; f < 4; f++){
                float wr = wp[2*f];
                float wi = wp[2*f+1];
                #pragma unroll
                for (int t = 0; t < 6; t++){
                    accx[f][t] = fmaf(a[t].x, wr, fmaf(-a[t].y, wi, accx[f][t]));
                    accy[f][t] = fmaf(a[t].x, wi, fmaf( a[t].y, wr, accy[f][t]));
                }
            }
        }
    }
    int h = h0 + ty, w = w0 + tx;
    #pragma unroll
    for (int f = 0; f < 4; f++){
        int fg = q*4 + f;
        float s = 0.f;
        #pragma unroll
        for (int t = 0; t < 6; t++) s += accx[f][t]*accx[f][t] + accy[f][t]*accy[f][t];
        float act_in = sqrtf(s) * (1.0f/6.0f);
        float pos = fminf(fmaxf(act_in * 34.0f, 0.0f), 34.0f);
        int i0 = (int)pos; if (i0 > 33) i0 = 33;
        float frac = pos - (float)i0;
        float k0v = knots[i0*24 + fg];
        float k1v = knots[(i0+1)*24 + fg];
        float aout = k0v*(1.0f - frac) + k1v*frac;
        #pragma unroll
        for (int t = 0; t < 6; t++)
            V[(long)(t*24+fg)*VPLANE + VIOFF + h*VSTRIDE + w] =
                make_float2(accx[f][t]*aout, accy[f][t]*aout);
    }
}

// ---------------- adjoint conv 24->1: 12 channels/block, async double-buffer -----
// z = part*6 + t ; part handles f in [12*part, 12*part+12); writes rg + part*NPIX
__global__ __launch_bounds__(256) void conv_adj_kernel(const float2* __restrict__ V,
                                                       const float* __restrict__ wa,
                                                       float2* __restrict__ rg){
    __shared__ __align__(16) float2 vt[2][42][26];   // 2 x 8736 B, 546 chunks each
    int z = blockIdx.z;
    int t = z % 6, part = z / 6;
    int h0 = blockIdx.y*32, w0 = blockIdx.x*16;
    int tx = threadIdx.x & 15;
    int r0 = (threadIdx.x >> 4) * 2;   // 0..30
    int wv = threadIdx.x >> 6, ln = threadIdx.x & 63;
    int f0 = part*12;

    const float2* gsrc[3];
    unsigned lofs[3];
    bool act[3];
    {
        const float2* plane0 = V + (long)(t*24 + f0)*VPLANE;
        #pragma unroll
        for (int r = 0; r < 3; r++){
            int s = r*256 + wv*64 + ln;
            act[r] = (s < 546);
            int row = s / 13;
            int col = s - row*13;
            gsrc[r] = plane0 + (long)(h0 + row)*VSTRIDE + w0 + col*2;
            lofs[r] = (unsigned)(r*256 + wv*64)*16u;
        }
    }
    {   // prologue: stage channel f0 into buf 0
        #pragma unroll
        for (int r = 0; r < 3; r++)
            if (act[r]) gl_lds16(gsrc[r], (char*)(&vt[0][0][0]) + lofs[r]);
    }
    float2 acc0 = make_float2(0.f,0.f), acc1 = make_float2(0.f,0.f);

    #pragma unroll 1
    for (int k = 0; k < 12; k++){
        int buf = k & 1;
        __syncthreads();   // drains vmcnt -> vt[buf] complete; prior readers of vt[buf^1] done
        if (k + 1 < 12){   // async-stage next channel into the other buffer
            #pragma unroll
            for (int r = 0; r < 3; r++){
                if (act[r]) gl_lds16(gsrc[r] + (long)VPLANE, (char*)(&vt[buf^1][0][0]) + lofs[r]);
                gsrc[r] += VPLANE;
            }
        }
        const float* wf = wa + (f0 + k)*242;
        #pragma unroll
        for (int sr = 0; sr < 12; sr++){
            float2 v[11];
            #pragma unroll
            for (int kx = 0; kx < 11; kx++) v[kx] = vt[buf][r0+sr][tx+kx];
            #pragma unroll
            for (int rr = 0; rr < 2; rr++){
                int ky = sr - rr;
                if (ky < 0 || ky > 10) continue;   // compile-time resolved
                float2* ac = rr ? &acc1 : &acc0;
                #pragma unroll
                for (int kx = 0; kx < 11; kx++){
                    float wr = wf[(ky*11+kx)*2+0];
                    float wi = wf[(ky*11+kx)*2+1];
                    ac->x = fmaf(v[kx].x, wr, fmaf( v[kx].y, wi, ac->x));
                    ac->y = fmaf(v[kx].y, wr, fmaf(-v[kx].x, wi, ac->y));
                }
            }
        }
    }
    float2* out = rg + (long)part*NPIX + (long)t*HW;
    out[(h0 + r0    )*256 + (w0 + tx)] = acc0;
    out[(h0 + r0 + 1)*256 + (w0 + tx)] = acc1;
}

// ---------------- fused data-consistency + momentum update --------------------
// dg = R+( mask/256 * R-(Ximg) ) - G ;  m = mu*m + alpha*dg + rg0 + rg1 ; Ximg -= m
__global__ void dc_update_kernel(float2* __restrict__ Xpad, float2* __restrict__ m,
                                 const float2* __restrict__ rg, const float2* __restrict__ G,
                                 const float* __restrict__ mask,
                                 const float* __restrict__ alphas, const float* __restrict__ moms,
                                 int l){
    __shared__ float2 lds[2][256];
    __shared__ float2 tw[128];    // e^{+i 2pi k/256}
    int tid = threadIdx.x;
    int line = tid >> 7;
    int j = tid & 127;
    if (tid < 128){
        float s, c;
        sincosf(6.283185307179586f * (float)tid / 256.0f, &s, &c);
        tw[tid] = make_float2(c, s);
    }
    long gl = (long)blockIdx.x*2 + line;   // = t*256 + h
    int t = (int)(gl >> 8);
    int h = (int)(gl & 255);
    float2* src = Xpad + (long)t*VPLANE + VIOFF + (long)h*VSTRIDE;
    float2 xo0, xo1;
    {   // load with (-1)^n
        float sg = (j & 1) ? -1.f : 1.f;
        xo0 = src[j]; xo1 = src[j+128];
        lds[line][j]     = make_float2(xo0.x*sg, xo0.y*sg);
        lds[line][j+128] = make_float2(xo1.x*sg, xo1.y*sg);
    }
    __syncthreads();
    // FFT1: DIF, dir = -1 (conj tw), natural in -> bit-reversed out
    for (int s = 0; s < 8; s++){
        int half = 128 >> s;
        int pos = j & (half-1);
        int grp = j >> (7-s);
        int i0 = (grp << (8-s)) + pos;
        int i1 = i0 + half;
        float2 u = lds[line][i0], v = lds[line][i1];
        float2 w = tw[pos << s]; w.y = -w.y;
        lds[line][i0] = make_float2(u.x+v.x, u.y+v.y);
        float2 d = make_float2(u.x-v.x, u.y-v.y);
        lds[line][i1] = cmulf(d, w);
        __syncthreads();
    }
    // middle: multiply by mask(natural k)/256; (-1)^k signs cancel between passes
    {
        int k1 = __brev((unsigned)j) >> 24;
        int k2 = __brev((unsigned)(j+128)) >> 24;
        float mv1 = mask[t*256 + k1] * (1.0f/256.0f);
        float mv2 = mask[t*256 + k2] * (1.0f/256.0f);
        float2 a = lds[line][j], b = lds[line][j+128];
        lds[line][j]     = make_float2(a.x*mv1, a.y*mv1);
        lds[line][j+128] = make_float2(b.x*mv2, b.y*mv2);
    }
    __syncthreads();
    // FFT2: DIT, dir = +1, bit-reversed in -> natural out
    for (int s = 0; s < 8; s++){
        int m2 = 1 << s;
        int pos = j & (m2-1);
        int grp = j >> s;
        int i0 = (grp << (s+1)) + pos;
        int i1 = i0 + m2;
        float2 u = lds[line][i0];
        float2 v = cmulf(lds[line][i1], tw[pos << (7-s)]);
        lds[line][i0] = make_float2(u.x+v.x, u.y+v.y);
        lds[line][i1] = make_float2(u.x-v.x, u.y-v.y);
        __syncthreads();
    }
    float a  = alphas[l];
    float mu = moms[l];
    float sg = (j & 1) ? -1.f : 1.f;
    #pragma unroll
    for (int half = 0; half < 2; half++){
        int k = j + half*128;
        long idx = gl*256 + k;
        float2 d = lds[line][k];
        d = make_float2(d.x*sg, d.y*sg);
        float2 g = G[idx];
        float2 r0 = rg[idx], r1 = rg[idx + NPIX];
        float2 grad = make_float2(fmaf(a, d.x - g.x, r0.x + r1.x),
                                  fmaf(a, d.y - g.y, r0.y + r1.y));
        float2 mv = m[idx];
        float2 mm = make_float2(fmaf(mu, mv.x, grad.x), fmaf(mu, mv.y, grad.y));
        m[idx] = mm;
        float2 xo = half ? xo1 : xo0;
        src[k] = make_float2(xo.x - mm.x, xo.y - mm.y);
    }
}

// ---------------- output: stack(real, imag)*norm (reads padded Ximg) ------------
__global__ void output_kernel(const float2* __restrict__ Xpad, const float* __restrict__ sums,
                              float* __restrict__ out){
    int i = blockIdx.x*256 + threadIdx.x;
    int t = i >> 16;
    int p = i & 65535;
    int h = p >> 8, w = p & 255;
    float norm = sqrtf(sums[0]/sums[1]);
    float2 v = Xpad[(long)t*VPLANE + VIOFF + h*VSTRIDE + w];
    out[2*i]   = v.x * norm;
    out[2*i+1] = v.y * norm;
}

extern "C" void kernel_launch(void* const* d_in, const int* in_sizes, int n_in,
                              void* d_out, int out_size, void* d_ws, size_t ws_size,
                              hipStream_t stream){
    const float* Xr    = (const float*)d_in[0];
    const float* Xi    = (const float*)d_in[1];
    const float* mask  = (const float*)d_in[2];
    const float* kr    = (const float*)d_in[3];
    const float* ki    = (const float*)d_in[4];
    const float* knots = (const float*)d_in[5];
    const float* alph  = (const float*)d_in[6];
    const float* moms  = (const float*)d_in[7];
    const float* k0    = (const float*)d_in[8];

    float*  ws   = (float*)d_ws;
    float*  sums = ws;                        // 2 floats used (pad to 16)
    float*  Wf   = ws + 16;                   // 8*121*48 floats
    float*  Wa   = Wf + 8*121*48;
    float2* Xks  = (float2*)(Wa + 8*121*48);
    float2* mbuf = Xks  + NPIX;
    float2* G    = mbuf + NPIX;
    float2* rg   = G    + NPIX;               // 2*NPIX partials; first NPIX doubles as init tmp
    float2* Xpad = rg   + 2*NPIX;             // 6 * VPLANE, padded image
    float2* V    = Xpad + TT*VPLANE;          // 144 * VPLANE, padded V

    const float OS = 1.0f/16.0f;              // ortho scale per 1D pass

    hipMemsetAsync(sums, 0, 2*sizeof(float), stream);
    hipMemsetAsync(mbuf, 0, (size_t)NPIX*sizeof(float2), stream);
    hipMemsetAsync(Xpad, 0, (size_t)TT*VPLANE*sizeof(float2), stream);       // zero halos
    hipMemsetAsync(V,    0, (size_t)NPLANES*VPLANE*sizeof(float2), stream);  // zero halos

    repack_kernel<<<(8*121*24 + 255)/256, 256, 0, stream>>>(kr, ki, Wf, Wa);
    reduce_kernel<<<384, 256, 0, stream>>>(Xr, Xi, mask, sums);
    normalize_kernel<<<NPIX/256, 256, 0, stream>>>(Xr, Xi, sums, Xks);

    // init: Xpad = k2i(Xks)*k0 (padded) ; G = k2i(Xks)
    fft_row_kernel<<<TT*128, 256, 0, stream>>>(Xks, rg, +1.0f, OS);
    fft_col_kernel<<<TT*(256/CPB), 256, 0, stream>>>(rg, Xpad, G, +1.0f, OS, k0);

    for (int l = 0; l < 8; l++){
        conv_fwd_act_kernel<<<dim3(16,16,6), 256, 0, stream>>>(
            Xpad, Wf + (long)l*121*48, knots + (long)l*KN*FC, V);
        conv_adj_kernel<<<dim3(16,8,2*TT), 256, 0, stream>>>(V, Wa + (long)l*24*242, rg);
        dc_update_kernel<<<TT*128, 256, 0, stream>>>(Xpad, mbuf, rg, G, mask, alph, moms, l);
    }

    output_kernel<<<NPIX/256, 256, 0, stream>>>(Xpad, sums, (float*)d_out);
}

// Round 7
// 1888.291 us; speedup vs baseline: 2.3663x; 1.0337x over previous
//
#include <hip/hip_runtime.h>
#include <math.h>

#define TT 6
#define FC 24
#define KN 35
#define HW 65536
#define NPIX (TT*HW)   // 393216
#define CPB 16         // columns per block in col-FFT

// padded plane geometry (float2 units): 5-halo on all sides, stride rounded for 16B chunks
#define VSTRIDE 272
#define VROWS   266
#define VPLANE  (VROWS*VSTRIDE)          // 72352 float2 per plane
#define VIOFF   (5*VSTRIDE + 5)          // interior origin
#define NPLANES (TT*FC)                  // 144
#define HALO_PER_PLANE 6816              // 10*272 + 256*16 float2
#define TOT_PLANES (TT + NPLANES)        // Xpad + V, contiguous

__device__ inline float2 cmulf(float2 a, float2 b){
    return make_float2(a.x*b.x - a.y*b.y, a.x*b.y + a.y*b.x);
}

__device__ inline void gl_lds16(const float2* g, void* l){
    __builtin_amdgcn_global_load_lds((const __attribute__((address_space(1))) unsigned int*)g,
                                     (__attribute__((address_space(3))) unsigned int*)l,
                                     16, 0, 0);
}

// ---------------- halo zero: clears 5-wide borders of all 150 padded planes -----
__global__ void halo_zero_kernel(float2* base){
    int gid = blockIdx.x*256 + threadIdx.x;
    if (gid >= TOT_PLANES*HALO_PER_PLANE) return;
    int p = gid / HALO_PER_PLANE;
    int i = gid - p*HALO_PER_PLANE;
    int row, col;
    if (i < 2720){                 // top 5 + bottom 5 full rows
        row = i / 272; col = i - row*272;
        if (row >= 5) row += 256;  // 5..9 -> 261..265
    } else {                       // middle rows: left 5 + right 11 cols
        int j = i - 2720;
        row = 5 + j/16;
        col = j & 15;
        if (col >= 5) col += 256;  // 5..15 -> 261..271
    }
    base[(long)p*VPLANE + (long)row*VSTRIDE + col] = make_float2(0.f, 0.f);
}

// ---------------- reduction: sum|X|^2 and sum(mask) ----------------
__global__ void reduce_kernel(const float* xr, const float* xi, const float* mask, float* sums){
    __shared__ float s1[256], s2[256];
    int tid = threadIdx.x;
    int gid = blockIdx.x*256 + tid;
    float a = 0.f, b = 0.f;
    for (int i = gid; i < NPIX; i += gridDim.x*256) a += xr[i]*xr[i] + xi[i]*xi[i];
    for (int i = gid; i < TT*256; i += gridDim.x*256) b += mask[i];
    s1[tid]=a; s2[tid]=b; __syncthreads();
    for (int off=128; off>0; off>>=1){
        if (tid<off){ s1[tid]+=s1[tid+off]; s2[tid]+=s2[tid+off]; }
        __syncthreads();
    }
    if (tid==0){ atomicAdd(&sums[0], s1[0]); atomicAdd(&sums[1], s2[0]); }
}

// ---------------- normalize: Xks = (xr + i xi)/norm ----------------
__global__ void normalize_kernel(const float* xr, const float* xi, const float* sums, float2* Xks){
    int i = blockIdx.x*256 + threadIdx.x;
    float inv = rsqrtf(sums[0]/sums[1]);
    Xks[i] = make_float2(xr[i]*inv, xi[i]*inv);
}

// ---------------- weight repack: fwd [l][tap][f][ri], adj [l][f][tap-flipped][ri] ----------------
__global__ void repack_kernel(const float* kr, const float* ki, float* Wf, float* Wa){
    int i = blockIdx.x*256 + threadIdx.x;
    if (i >= 8*121*24) return;
    int f   = i % 24;
    int tap = (i/24) % 121;
    int l   = i/(24*121);
    long src = (long)(l*24+f)*121;
    Wf[(((long)l*121+tap)*24+f)*2+0] = kr[src+tap];
    Wf[(((long)l*121+tap)*24+f)*2+1] = ki[src+tap];
    Wa[(((long)l*24+f)*121+tap)*2+0] = kr[src+120-tap];   // spatial flip baked in
    Wa[(((long)l*24+f)*121+tap)*2+1] = ki[src+120-tap];
}

// ---------------- FFT row pass (init only), centered, 2 lines/block ----------------
__global__ void fft_row_kernel(const float2* __restrict__ in, float2* __restrict__ out,
                               float dir, float scale){
    __shared__ float2 lds[2][256];
    __shared__ float2 tw[128];
    int tid = threadIdx.x;
    int line = tid >> 7;
    int j = tid & 127;
    if (tid < 128){
        float s, c;
        sincosf(dir * 6.283185307179586f * (float)tid / 256.0f, &s, &c);
        tw[tid] = make_float2(c, s);
    }
    long gline = (long)blockIdx.x*2 + line;
    const float2* src = in + gline*256;
    {
        float sg = (j & 1) ? -1.f : 1.f;
        float2 a = src[j];
        float2 b = src[j+128];
        lds[line][j]     = make_float2(a.x*sg, a.y*sg);
        lds[line][j+128] = make_float2(b.x*sg, b.y*sg);
    }
    __syncthreads();
    for (int s = 0; s < 8; s++){
        int half = 128 >> s;
        int pos = j & (half-1);
        int grp = j >> (7-s);
        int i0 = (grp << (8-s)) + pos;
        int i1 = i0 + half;
        float2 u = lds[line][i0], v = lds[line][i1];
        float2 w = tw[pos << s];
        lds[line][i0] = make_float2(u.x+v.x, u.y+v.y);
        float2 d = make_float2(u.x-v.x, u.y-v.y);
        lds[line][i1] = cmulf(d, w);
        __syncthreads();
    }
    float2* dst = out + gline*256;
    {
        int k = j;
        float sg = (k & 1) ? -scale : scale;
        float2 v = lds[line][__brev((unsigned)k) >> 24];
        dst[k] = make_float2(v.x*sg, v.y*sg);
        k = j + 128;
        sg = (k & 1) ? -scale : scale;
        v = lds[line][__brev((unsigned)k) >> 24];
        dst[k] = make_float2(v.x*sg, v.y*sg);
    }
}

// ---------------- FFT col pass (init only): writes Xpad (*k0, padded) and G ------
__global__ void fft_col_kernel(const float2* __restrict__ in, float2* __restrict__ Xpad,
                               float2* __restrict__ G, float dir, float scale, const float* k0){
    __shared__ float2 lds[256][CPB+1];
    __shared__ float2 tw[128];
    int tid = threadIdx.x;
    if (tid < 128){
        float s, c;
        sincosf(dir * 6.283185307179586f * (float)tid / 256.0f, &s, &c);
        tw[tid] = make_float2(c, s);
    }
    int t  = blockIdx.x / (256/CPB);
    int w0 = (blockIdx.x % (256/CPB)) * CPB;
    const float2* src = in + (long)t*HW;
    int c  = tid & (CPB-1);
    int h0 = tid >> 4;
    for (int i = 0; i < 16; i++){
        int h = h0 + 16*i;
        float2 v = src[h*256 + w0 + c];
        float sg = (h & 1) ? -1.f : 1.f;
        lds[h][c] = make_float2(v.x*sg, v.y*sg);
    }
    __syncthreads();
    int jb = tid >> 4;
    for (int s = 0; s < 8; s++){
        int half = 128 >> s;
        for (int i = 0; i < 8; i++){
            int j = jb + 16*i;
            int pos = j & (half-1);
            int grp = j >> (7-s);
            int i0 = (grp << (8-s)) + pos;
            int i1 = i0 + half;
            float2 u = lds[i0][c], v = lds[i1][c];
            float2 w = tw[pos << s];
            lds[i0][c] = make_float2(u.x+v.x, u.y+v.y);
            float2 d = make_float2(u.x-v.x, u.y-v.y);
            lds[i1][c] = cmulf(d, w);
        }
        __syncthreads();
    }
    float kk = *k0;
    for (int i = 0; i < 16; i++){
        int k = h0 + 16*i;
        float2 v = lds[__brev((unsigned)k) >> 24][c];
        float sg = (k & 1) ? -scale : scale;
        float2 g = make_float2(v.x*sg, v.y*sg);
        G[(long)t*HW + k*256 + w0 + c] = g;
        Xpad[(long)t*VPLANE + VIOFF + k*VSTRIDE + w0 + c] = make_float2(g.x*kk, g.y*kk);
    }
}

// ---------------- fused forward conv (1->24) + spline act: async staging ---------
__global__ __launch_bounds__(256) void conv_fwd_act_kernel(
        const float2* __restrict__ Xpad, const float* __restrict__ wt,
        const float* __restrict__ knots, float2* __restrict__ V){
    __shared__ __align__(16) float2 xt[6][26][26];   // 338 chunks/plane, 2028 total
    int q  = blockIdx.z;
    int h0 = blockIdx.y*16, w0 = blockIdx.x*16;
    int tx = threadIdx.x & 15, ty = threadIdx.x >> 4;
    int wv = threadIdx.x >> 6, ln = threadIdx.x & 63;
    {
        #pragma unroll
        for (int r = 0; r < 8; r++){
            int s = r*256 + wv*64 + ln;
            if (s < 2028){
                int t = s / 338, rem = s - t*338;
                int row = rem / 13, col = rem - row*13;
                const float2* g = Xpad + (long)t*VPLANE + (long)(h0 + row)*VSTRIDE + w0 + col*2;
                gl_lds16(g, (char*)(&xt[0][0][0]) + (unsigned)(r*256 + wv*64)*16u);
            }
        }
    }
    __syncthreads();
    float accx[4][6], accy[4][6];   // [f][t]
    #pragma unroll
    for (int f = 0; f < 4; f++)
        #pragma unroll
        for (int t = 0; t < 6; t++){ accx[f][t] = 0.f; accy[f][t] = 0.f; }
    for (int ky = 0; ky < 11; ky++){
        #pragma unroll
        for (int kx = 0; kx < 11; kx++){
            const float* wp = wt + (ky*11 + kx)*48 + q*8;
            float2 a[6];
            #pragma unroll
            for (int t = 0; t < 6; t++) a[t] = xt[t][ty+ky][tx+kx];
            #pragma unroll
            for (int f = 0; f < 4; f++){
                float wr = wp[2*f];
                float wi = wp[2*f+1];
                #pragma unroll
                for (int t = 0; t < 6; t++){
                    accx[f][t] = fmaf(a[t].x, wr, fmaf(-a[t].y, wi, accx[f][t]));
                    accy[f][t] = fmaf(a[t].x, wi, fmaf( a[t].y, wr, accy[f][t]));
                }
            }
        }
    }
    int h = h0 + ty, w = w0 + tx;
    #pragma unroll
    for (int f = 0; f < 4; f++){
        int fg = q*4 + f;
        float s = 0.f;
        #pragma unroll
        for (int t = 0; t < 6; t++) s += accx[f][t]*accx[f][t] + accy[f][t]*accy[f][t];
        float act_in = sqrtf(s) * (1.0f/6.0f);
        float pos = fminf(fmaxf(act_in * 34.0f, 0.0f), 34.0f);
        int i0 = (int)pos; if (i0 > 33) i0 = 33;
        float frac = pos - (float)i0;
        float k0v = knots[i0*24 + fg];
        float k1v = knots[(i0+1)*24 + fg];
        float aout = k0v*(1.0f - frac) + k1v*frac;
        #pragma unroll
        for (int t = 0; t < 6; t++)
            V[(long)(t*24+fg)*VPLANE + VIOFF + h*VSTRIDE + w] =
                make_float2(accx[f][t]*aout, accy[f][t]*aout);
    }
}

// ---------------- adjoint conv 24->1: 6 channels/block, async double-buffer ------
// z = part*6 + t ; part handles f in [6*part, 6*part+6); writes rg + part*NPIX
__global__ __launch_bounds__(256) void conv_adj_kernel(const float2* __restrict__ V,
                                                       const float* __restrict__ wa,
                                                       float2* __restrict__ rg){
    __shared__ __align__(16) float2 vt[2][42][26];   // 2 x 8736 B, 546 chunks each
    int z = blockIdx.z;
    int t = z % 6, part = z / 6;      // part 0..3
    int h0 = blockIdx.y*32, w0 = blockIdx.x*16;
    int tx = threadIdx.x & 15;
    int r0 = (threadIdx.x >> 4) * 2;  // 0..30
    int wv = threadIdx.x >> 6, ln = threadIdx.x & 63;
    int f0 = part*6;

    const float2* gsrc[3];
    unsigned lofs[3];
    bool act[3];
    {
        const float2* plane0 = V + (long)(t*24 + f0)*VPLANE;
        #pragma unroll
        for (int r = 0; r < 3; r++){
            int s = r*256 + wv*64 + ln;
            act[r] = (s < 546);
            int row = s / 13;
            int col = s - row*13;
            gsrc[r] = plane0 + (long)(h0 + row)*VSTRIDE + w0 + col*2;
            lofs[r] = (unsigned)(r*256 + wv*64)*16u;
        }
    }
    {   // prologue: stage channel f0 into buf 0
        #pragma unroll
        for (int r = 0; r < 3; r++)
            if (act[r]) gl_lds16(gsrc[r], (char*)(&vt[0][0][0]) + lofs[r]);
    }
    float2 acc0 = make_float2(0.f,0.f), acc1 = make_float2(0.f,0.f);

    #pragma unroll 1
    for (int k = 0; k < 6; k++){
        int buf = k & 1;
        __syncthreads();   // drains vmcnt -> vt[buf] complete; prior readers of vt[buf^1] done
        if (k + 1 < 6){    // async-stage next channel into the other buffer
            #pragma unroll
            for (int r = 0; r < 3; r++){
                if (act[r]) gl_lds16(gsrc[r] + (long)VPLANE, (char*)(&vt[buf^1][0][0]) + lofs[r]);
                gsrc[r] += VPLANE;
            }
        }
        const float* wf = wa + (f0 + k)*242;
        #pragma unroll
        for (int sr = 0; sr < 12; sr++){
            float2 v[11];
            #pragma unroll
            for (int kx = 0; kx < 11; kx++) v[kx] = vt[buf][r0+sr][tx+kx];
            #pragma unroll
            for (int rr = 0; rr < 2; rr++){
                int ky = sr - rr;
                if (ky < 0 || ky > 10) continue;   // compile-time resolved
                float2* ac = rr ? &acc1 : &acc0;
                #pragma unroll
                for (int kx = 0; kx < 11; kx++){
                    float wr = wf[(ky*11+kx)*2+0];
                    float wi = wf[(ky*11+kx)*2+1];
                    ac->x = fmaf(v[kx].x, wr, fmaf( v[kx].y, wi, ac->x));
                    ac->y = fmaf(v[kx].y, wr, fmaf(-v[kx].x, wi, ac->y));
                }
            }
        }
    }
    float2* out = rg + (long)part*NPIX + (long)t*HW;
    out[(h0 + r0    )*256 + (w0 + tx)] = acc0;
    out[(h0 + r0 + 1)*256 + (w0 + tx)] = acc1;
}

// ---------------- fused data-consistency + momentum update --------------------
// dg = R+( mask/256 * R-(Ximg) ) - G ;  m = mu*m + alpha*dg + sum(rg parts) ; Ximg -= m
__global__ void dc_update_kernel(float2* __restrict__ Xpad, float2* __restrict__ m,
                                 const float2* __restrict__ rg, const float2* __restrict__ G,
                                 const float* __restrict__ mask,
                                 const float* __restrict__ alphas, const float* __restrict__ moms,
                                 int l){
    __shared__ float2 lds[2][256];
    __shared__ float2 tw[128];    // e^{+i 2pi k/256}
    int tid = threadIdx.x;
    int line = tid >> 7;
    int j = tid & 127;
    if (tid < 128){
        float s, c;
        sincosf(6.283185307179586f * (float)tid / 256.0f, &s, &c);
        tw[tid] = make_float2(c, s);
    }
    long gl = (long)blockIdx.x*2 + line;   // = t*256 + h
    int t = (int)(gl >> 8);
    int h = (int)(gl & 255);
    float2* src = Xpad + (long)t*VPLANE + VIOFF + (long)h*VSTRIDE;
    float2 xo0, xo1;
    {   // load with (-1)^n
        float sg = (j & 1) ? -1.f : 1.f;
        xo0 = src[j]; xo1 = src[j+128];
        lds[line][j]     = make_float2(xo0.x*sg, xo0.y*sg);
        lds[line][j+128] = make_float2(xo1.x*sg, xo1.y*sg);
    }
    __syncthreads();
    // FFT1: DIF, dir = -1 (conj tw), natural in -> bit-reversed out
    for (int s = 0; s < 8; s++){
        int half = 128 >> s;
        int pos = j & (half-1);
        int grp = j >> (7-s);
        int i0 = (grp << (8-s)) + pos;
        int i1 = i0 + half;
        float2 u = lds[line][i0], v = lds[line][i1];
        float2 w = tw[pos << s]; w.y = -w.y;
        lds[line][i0] = make_float2(u.x+v.x, u.y+v.y);
        float2 d = make_float2(u.x-v.x, u.y-v.y);
        lds[line][i1] = cmulf(d, w);
        __syncthreads();
    }
    // middle: multiply by mask(natural k)/256; (-1)^k signs cancel between passes
    {
        int k1 = __brev((unsigned)j) >> 24;
        int k2 = __brev((unsigned)(j+128)) >> 24;
        float mv1 = mask[t*256 + k1] * (1.0f/256.0f);
        float mv2 = mask[t*256 + k2] * (1.0f/256.0f);
        float2 a = lds[line][j], b = lds[line][j+128];
        lds[line][j]     = make_float2(a.x*mv1, a.y*mv1);
        lds[line][j+128] = make_float2(b.x*mv2, b.y*mv2);
    }
    __syncthreads();
    // FFT2: DIT, dir = +1, bit-reversed in -> natural out
    for (int s = 0; s < 8; s++){
        int m2 = 1 << s;
        int pos = j & (m2-1);
        int grp = j >> s;
        int i0 = (grp << (s+1)) + pos;
        int i1 = i0 + m2;
        float2 u = lds[line][i0];
        float2 v = cmulf(lds[line][i1], tw[pos << (7-s)]);
        lds[line][i0] = make_float2(u.x+v.x, u.y+v.y);
        lds[line][i1] = make_float2(u.x-v.x, u.y-v.y);
        __syncthreads();
    }
    float a  = alphas[l];
    float mu = moms[l];
    float sg = (j & 1) ? -1.f : 1.f;
    #pragma unroll
    for (int half = 0; half < 2; half++){
        int k = j + half*128;
        long idx = gl*256 + k;
        float2 d = lds[line][k];
        d = make_float2(d.x*sg, d.y*sg);
        float2 g = G[idx];
        float2 r0 = rg[idx],          r1 = rg[idx + NPIX];
        float2 r2 = rg[idx + 2*NPIX], r3 = rg[idx + 3*NPIX];
        float rx = (r0.x + r1.x) + (r2.x + r3.x);
        float ry = (r0.y + r1.y) + (r2.y + r3.y);
        float2 grad = make_float2(fmaf(a, d.x - g.x, rx), fmaf(a, d.y - g.y, ry));
        float2 mm;
        if (l == 0){
            mm = grad;                       // m starts at zero; skip poisoned read
        } else {
            float2 mv = m[idx];
            mm = make_float2(fmaf(mu, mv.x, grad.x), fmaf(mu, mv.y, grad.y));
        }
        m[idx] = mm;
        float2 xo = half ? xo1 : xo0;
        src[k] = make_float2(xo.x - mm.x, xo.y - mm.y);
    }
}

// ---------------- output: stack(real, imag)*norm (reads padded Ximg) ------------
__global__ void output_kernel(const float2* __restrict__ Xpad, const float* __restrict__ sums,
                              float* __restrict__ out){
    int i = blockIdx.x*256 + threadIdx.x;
    int t = i >> 16;
    int p = i & 65535;
    int h = p >> 8, w = p & 255;
    float norm = sqrtf(sums[0]/sums[1]);
    float2 v = Xpad[(long)t*VPLANE + VIOFF + h*VSTRIDE + w];
    out[2*i]   = v.x * norm;
    out[2*i+1] = v.y * norm;
}

extern "C" void kernel_launch(void* const* d_in, const int* in_sizes, int n_in,
                              void* d_out, int out_size, void* d_ws, size_t ws_size,
                              hipStream_t stream){
    const float* Xr    = (const float*)d_in[0];
    const float* Xi    = (const float*)d_in[1];
    const float* mask  = (const float*)d_in[2];
    const float* kr    = (const float*)d_in[3];
    const float* ki    = (const float*)d_in[4];
    const float* knots = (const float*)d_in[5];
    const float* alph  = (const float*)d_in[6];
    const float* moms  = (const float*)d_in[7];
    const float* k0    = (const float*)d_in[8];

    float*  ws   = (float*)d_ws;
    float*  sums = ws;                        // 2 floats used (pad to 16)
    float*  Wf   = ws + 16;                   // 8*121*48 floats
    float*  Wa   = Wf + 8*121*48;
    float2* Xks  = (float2*)(Wa + 8*121*48);
    float2* mbuf = Xks  + NPIX;
    float2* G    = mbuf + NPIX;
    float2* rg   = G    + NPIX;               // 4*NPIX partials; first NPIX doubles as init tmp
    float2* Xpad = rg   + 4*NPIX;             // 6 * VPLANE, padded image
    float2* V    = Xpad + TT*VPLANE;          // 144 * VPLANE, padded V (contiguous after Xpad)

    const float OS = 1.0f/16.0f;              // ortho scale per 1D pass

    hipMemsetAsync(sums, 0, 2*sizeof(float), stream);
    halo_zero_kernel<<<(TOT_PLANES*HALO_PER_PLANE + 255)/256, 256, 0, stream>>>(Xpad);

    repack_kernel<<<(8*121*24 + 255)/256, 256, 0, stream>>>(kr, ki, Wf, Wa);
    reduce_kernel<<<384, 256, 0, stream>>>(Xr, Xi, mask, sums);
    normalize_kernel<<<NPIX/256, 256, 0, stream>>>(Xr, Xi, sums, Xks);

    // init: Xpad = k2i(Xks)*k0 (padded) ; G = k2i(Xks)
    fft_row_kernel<<<TT*128, 256, 0, stream>>>(Xks, rg, +1.0f, OS);
    fft_col_kernel<<<TT*(256/CPB), 256, 0, stream>>>(rg, Xpad, G, +1.0f, OS, k0);

    for (int l = 0; l < 8; l++){
        conv_fwd_act_kernel<<<dim3(16,16,6), 256, 0, stream>>>(
            Xpad, Wf + (long)l*121*48, knots + (long)l*KN*FC, V);
        conv_adj_kernel<<<dim3(16,8,4*TT), 256, 0, stream>>>(V, Wa + (long)l*24*242, rg);
        dc_update_kernel<<<TT*128, 256, 0, stream>>>(Xpad, mbuf, rg, G, mask, alph, moms, l);
    }

    output_kernel<<<NPIX/256, 256, 0, stream>>>(Xpad, sums, (float*)d_out);
}

// Round 8
// 1864.273 us; speedup vs baseline: 2.3968x; 1.0129x over previous
//
#include <hip/hip_runtime.h>
#include <math.h>

#define TT 6
#define FC 24
#define KN 35
#define HW 65536
#define NPIX (TT*HW)   // 393216
#define CPB 16         // columns per block in col-FFT

// padded plane geometry (float2 units): 5-halo on all sides, stride rounded for 16B chunks
#define VSTRIDE 272
#define VROWS   266
#define VPLANE  (VROWS*VSTRIDE)          // 72352 float2 per plane
#define VIOFF   (5*VSTRIDE + 5)          // interior origin
#define NPLANES (TT*FC)                  // 144
#define HALO_PER_PLANE 6816              // 10*272 + 256*16 float2
#define TOT_PLANES (TT + NPLANES)        // Xpad + V, contiguous

typedef float v2f __attribute__((ext_vector_type(2)));

__device__ inline float2 cmulf(float2 a, float2 b){
    return make_float2(a.x*b.x - a.y*b.y, a.x*b.y + a.y*b.x);
}

__device__ inline void gl_lds16(const float2* g, void* l){
    __builtin_amdgcn_global_load_lds((const __attribute__((address_space(1))) unsigned int*)g,
                                     (__attribute__((address_space(3))) unsigned int*)l,
                                     16, 0, 0);
}

// ---------------- halo zero: clears 5-wide borders of all 150 padded planes -----
__global__ void halo_zero_kernel(float2* base){
    int gid = blockIdx.x*256 + threadIdx.x;
    if (gid >= TOT_PLANES*HALO_PER_PLANE) return;
    int p = gid / HALO_PER_PLANE;
    int i = gid - p*HALO_PER_PLANE;
    int row, col;
    if (i < 2720){                 // top 5 + bottom 5 full rows
        row = i / 272; col = i - row*272;
        if (row >= 5) row += 256;  // 5..9 -> 261..265
    } else {                       // middle rows: left 5 + right 11 cols
        int j = i - 2720;
        row = 5 + j/16;
        col = j & 15;
        if (col >= 5) col += 256;  // 5..15 -> 261..271
    }
    base[(long)p*VPLANE + (long)row*VSTRIDE + col] = make_float2(0.f, 0.f);
}

// ---------------- reduction: sum|X|^2 and sum(mask) ----------------
__global__ void reduce_kernel(const float* xr, const float* xi, const float* mask, float* sums){
    __shared__ float s1[256], s2[256];
    int tid = threadIdx.x;
    int gid = blockIdx.x*256 + tid;
    float a = 0.f, b = 0.f;
    for (int i = gid; i < NPIX; i += gridDim.x*256) a += xr[i]*xr[i] + xi[i]*xi[i];
    for (int i = gid; i < TT*256; i += gridDim.x*256) b += mask[i];
    s1[tid]=a; s2[tid]=b; __syncthreads();
    for (int off=128; off>0; off>>=1){
        if (tid<off){ s1[tid]+=s1[tid+off]; s2[tid]+=s2[tid+off]; }
        __syncthreads();
    }
    if (tid==0){ atomicAdd(&sums[0], s1[0]); atomicAdd(&sums[1], s2[0]); }
}

// ---------------- normalize: Xks = (xr + i xi)/norm ----------------
__global__ void normalize_kernel(const float* xr, const float* xi, const float* sums, float2* Xks){
    int i = blockIdx.x*256 + threadIdx.x;
    float inv = rsqrtf(sums[0]/sums[1]);
    Xks[i] = make_float2(xr[i]*inv, xi[i]*inv);
}

// ---------------- weight repack: fwd [l][tap][f][ri], adj [l][f][tap-flipped][ri] ----------------
__global__ void repack_kernel(const float* kr, const float* ki, float* Wf, float* Wa){
    int i = blockIdx.x*256 + threadIdx.x;
    if (i >= 8*121*24) return;
    int f   = i % 24;
    int tap = (i/24) % 121;
    int l   = i/(24*121);
    long src = (long)(l*24+f)*121;
    Wf[(((long)l*121+tap)*24+f)*2+0] = kr[src+tap];
    Wf[(((long)l*121+tap)*24+f)*2+1] = ki[src+tap];
    Wa[(((long)l*24+f)*121+tap)*2+0] = kr[src+120-tap];   // spatial flip baked in
    Wa[(((long)l*24+f)*121+tap)*2+1] = ki[src+120-tap];
}

// ---------------- FFT row pass (init only), centered, 2 lines/block ----------------
__global__ void fft_row_kernel(const float2* __restrict__ in, float2* __restrict__ out,
                               float dir, float scale){
    __shared__ float2 lds[2][256];
    __shared__ float2 tw[128];
    int tid = threadIdx.x;
    int line = tid >> 7;
    int j = tid & 127;
    if (tid < 128){
        float s, c;
        sincosf(dir * 6.283185307179586f * (float)tid / 256.0f, &s, &c);
        tw[tid] = make_float2(c, s);
    }
    long gline = (long)blockIdx.x*2 + line;
    const float2* src = in + gline*256;
    {
        float sg = (j & 1) ? -1.f : 1.f;
        float2 a = src[j];
        float2 b = src[j+128];
        lds[line][j]     = make_float2(a.x*sg, a.y*sg);
        lds[line][j+128] = make_float2(b.x*sg, b.y*sg);
    }
    __syncthreads();
    for (int s = 0; s < 8; s++){
        int half = 128 >> s;
        int pos = j & (half-1);
        int grp = j >> (7-s);
        int i0 = (grp << (8-s)) + pos;
        int i1 = i0 + half;
        float2 u = lds[line][i0], v = lds[line][i1];
        float2 w = tw[pos << s];
        lds[line][i0] = make_float2(u.x+v.x, u.y+v.y);
        float2 d = make_float2(u.x-v.x, u.y-v.y);
        lds[line][i1] = cmulf(d, w);
        __syncthreads();
    }
    float2* dst = out + gline*256;
    {
        int k = j;
        float sg = (k & 1) ? -scale : scale;
        float2 v = lds[line][__brev((unsigned)k) >> 24];
        dst[k] = make_float2(v.x*sg, v.y*sg);
        k = j + 128;
        sg = (k & 1) ? -scale : scale;
        v = lds[line][__brev((unsigned)k) >> 24];
        dst[k] = make_float2(v.x*sg, v.y*sg);
    }
}

// ---------------- FFT col pass (init only): writes Xpad (*k0, padded) and G ------
__global__ void fft_col_kernel(const float2* __restrict__ in, float2* __restrict__ Xpad,
                               float2* __restrict__ G, float dir, float scale, const float* k0){
    __shared__ float2 lds[256][CPB+1];
    __shared__ float2 tw[128];
    int tid = threadIdx.x;
    if (tid < 128){
        float s, c;
        sincosf(dir * 6.283185307179586f * (float)tid / 256.0f, &s, &c);
        tw[tid] = make_float2(c, s);
    }
    int t  = blockIdx.x / (256/CPB);
    int w0 = (blockIdx.x % (256/CPB)) * CPB;
    const float2* src = in + (long)t*HW;
    int c  = tid & (CPB-1);
    int h0 = tid >> 4;
    for (int i = 0; i < 16; i++){
        int h = h0 + 16*i;
        float2 v = src[h*256 + w0 + c];
        float sg = (h & 1) ? -1.f : 1.f;
        lds[h][c] = make_float2(v.x*sg, v.y*sg);
    }
    __syncthreads();
    int jb = tid >> 4;
    for (int s = 0; s < 8; s++){
        int half = 128 >> s;
        for (int i = 0; i < 8; i++){
            int j = jb + 16*i;
            int pos = j & (half-1);
            int grp = j >> (7-s);
            int i0 = (grp << (8-s)) + pos;
            int i1 = i0 + half;
            float2 u = lds[i0][c], v = lds[i1][c];
            float2 w = tw[pos << s];
            lds[i0][c] = make_float2(u.x+v.x, u.y+v.y);
            float2 d = make_float2(u.x-v.x, u.y-v.y);
            lds[i1][c] = cmulf(d, w);
        }
        __syncthreads();
    }
    float kk = *k0;
    for (int i = 0; i < 16; i++){
        int k = h0 + 16*i;
        float2 v = lds[__brev((unsigned)k) >> 24][c];
        float sg = (k & 1) ? -scale : scale;
        float2 g = make_float2(v.x*sg, v.y*sg);
        G[(long)t*HW + k*256 + w0 + c] = g;
        Xpad[(long)t*VPLANE + VIOFF + k*VSTRIDE + w0 + c] = make_float2(g.x*kk, g.y*kk);
    }
}

// ---------------- fused forward conv (1->24) + spline act: packed fp32 -----------
// q = blockIdx.z (0..11): f in {2q, 2q+1}. Packed accumulators: accR = sum a*wr,
// accW = sum a*wi; DXr = accR.x - accW.y, DXi = accR.y + accW.x (2 pk-fma per tap).
__global__ __launch_bounds__(256) void conv_fwd_act_kernel(
        const float2* __restrict__ Xpad, const float* __restrict__ wt,
        const float* __restrict__ knots, float2* __restrict__ V){
    __shared__ __align__(16) float2 xt[6][26][26];   // 338 chunks/plane, 2028 total
    int q  = blockIdx.z;
    int h0 = blockIdx.y*16, w0 = blockIdx.x*16;
    int tx = threadIdx.x & 15, ty = threadIdx.x >> 4;
    int wv = threadIdx.x >> 6, ln = threadIdx.x & 63;
    {
        #pragma unroll
        for (int r = 0; r < 8; r++){
            int s = r*256 + wv*64 + ln;
            if (s < 2028){
                int t = s / 338, rem = s - t*338;
                int row = rem / 13, col = rem - row*13;
                const float2* g = Xpad + (long)t*VPLANE + (long)(h0 + row)*VSTRIDE + w0 + col*2;
                gl_lds16(g, (char*)(&xt[0][0][0]) + (unsigned)(r*256 + wv*64)*16u);
            }
        }
    }
    __syncthreads();
    v2f accR[2][6], accW[2][6];   // [f][t]
    #pragma unroll
    for (int f = 0; f < 2; f++)
        #pragma unroll
        for (int t = 0; t < 6; t++){ accR[f][t] = (v2f)(0.f); accW[f][t] = (v2f)(0.f); }
    for (int ky = 0; ky < 11; ky++){
        #pragma unroll
        for (int kx = 0; kx < 11; kx++){
            const float* wp = wt + (ky*11 + kx)*48 + q*4;
            v2f a[6];
            #pragma unroll
            for (int t = 0; t < 6; t++) a[t] = *(const v2f*)&xt[t][ty+ky][tx+kx];
            #pragma unroll
            for (int f = 0; f < 2; f++){
                v2f wrv = (v2f)(wp[2*f]);
                v2f wiv = (v2f)(wp[2*f+1]);
                #pragma unroll
                for (int t = 0; t < 6; t++){
                    accR[f][t] = __builtin_elementwise_fma(a[t], wrv, accR[f][t]);
                    accW[f][t] = __builtin_elementwise_fma(a[t], wiv, accW[f][t]);
                }
            }
        }
    }
    int h = h0 + ty, w = w0 + tx;
    #pragma unroll
    for (int f = 0; f < 2; f++){
        int fg = q*2 + f;
        float dxr[6], dxi[6];
        float s = 0.f;
        #pragma unroll
        for (int t = 0; t < 6; t++){
            dxr[t] = accR[f][t].x - accW[f][t].y;
            dxi[t] = accR[f][t].y + accW[f][t].x;
            s += dxr[t]*dxr[t] + dxi[t]*dxi[t];
        }
        float act_in = sqrtf(s) * (1.0f/6.0f);
        float pos = fminf(fmaxf(act_in * 34.0f, 0.0f), 34.0f);
        int i0 = (int)pos; if (i0 > 33) i0 = 33;
        float frac = pos - (float)i0;
        float k0v = knots[i0*24 + fg];
        float k1v = knots[(i0+1)*24 + fg];
        float aout = k0v*(1.0f - frac) + k1v*frac;
        #pragma unroll
        for (int t = 0; t < 6; t++)
            V[(long)(t*24+fg)*VPLANE + VIOFF + h*VSTRIDE + w] =
                make_float2(dxr[t]*aout, dxi[t]*aout);
    }
}

// ---------------- adjoint conv 24->1: 6 ch/block, async dbuf, packed fp32 --------
// z = part*6 + t ; part handles f in [6*part, 6*part+6); writes rg + part*NPIX
// accR = sum v*wr, accW = sum v*wi; out = (accR.x + accW.y, accR.y - accW.x)
__global__ __launch_bounds__(256) void conv_adj_kernel(const float2* __restrict__ V,
                                                       const float* __restrict__ wa,
                                                       float2* __restrict__ rg){
    __shared__ __align__(16) float2 vt[2][42][26];   // 2 x 8736 B, 546 chunks each
    int z = blockIdx.z;
    int t = z % 6, part = z / 6;      // part 0..3
    int h0 = blockIdx.y*32, w0 = blockIdx.x*16;
    int tx = threadIdx.x & 15;
    int r0 = (threadIdx.x >> 4) * 2;  // 0..30
    int wv = threadIdx.x >> 6, ln = threadIdx.x & 63;
    int f0 = part*6;

    const float2* gsrc[3];
    unsigned lofs[3];
    bool act[3];
    {
        const float2* plane0 = V + (long)(t*24 + f0)*VPLANE;
        #pragma unroll
        for (int r = 0; r < 3; r++){
            int s = r*256 + wv*64 + ln;
            act[r] = (s < 546);
            int row = s / 13;
            int col = s - row*13;
            gsrc[r] = plane0 + (long)(h0 + row)*VSTRIDE + w0 + col*2;
            lofs[r] = (unsigned)(r*256 + wv*64)*16u;
        }
    }
    {   // prologue: stage channel f0 into buf 0
        #pragma unroll
        for (int r = 0; r < 3; r++)
            if (act[r]) gl_lds16(gsrc[r], (char*)(&vt[0][0][0]) + lofs[r]);
    }
    v2f accR0 = (v2f)(0.f), accW0 = (v2f)(0.f);
    v2f accR1 = (v2f)(0.f), accW1 = (v2f)(0.f);

    #pragma unroll 1
    for (int k = 0; k < 6; k++){
        int buf = k & 1;
        __syncthreads();   // drains vmcnt -> vt[buf] complete; prior readers of vt[buf^1] done
        if (k + 1 < 6){    // async-stage next channel into the other buffer
            #pragma unroll
            for (int r = 0; r < 3; r++){
                if (act[r]) gl_lds16(gsrc[r] + (long)VPLANE, (char*)(&vt[buf^1][0][0]) + lofs[r]);
                gsrc[r] += VPLANE;
            }
        }
        const float* wf = wa + (f0 + k)*242;
        #pragma unroll
        for (int sr = 0; sr < 12; sr++){
            v2f v[11];
            #pragma unroll
            for (int kx = 0; kx < 11; kx++) v[kx] = *(const v2f*)&vt[buf][r0+sr][tx+kx];
            #pragma unroll
            for (int rr = 0; rr < 2; rr++){
                int ky = sr - rr;
                if (ky < 0 || ky > 10) continue;   // compile-time resolved
                #pragma unroll
                for (int kx = 0; kx < 11; kx++){
                    v2f wrv = (v2f)(wf[(ky*11+kx)*2+0]);
                    v2f wiv = (v2f)(wf[(ky*11+kx)*2+1]);
                    if (rr == 0){
                        accR0 = __builtin_elementwise_fma(v[kx], wrv, accR0);
                        accW0 = __builtin_elementwise_fma(v[kx], wiv, accW0);
                    } else {
                        accR1 = __builtin_elementwise_fma(v[kx], wrv, accR1);
                        accW1 = __builtin_elementwise_fma(v[kx], wiv, accW1);
                    }
                }
            }
        }
    }
    float2* out = rg + (long)part*NPIX + (long)t*HW;
    out[(h0 + r0    )*256 + (w0 + tx)] = make_float2(accR0.x + accW0.y, accR0.y - accW0.x);
    out[(h0 + r0 + 1)*256 + (w0 + tx)] = make_float2(accR1.x + accW1.y, accR1.y - accW1.x);
}

// ---------------- fused data-consistency + momentum update --------------------
// dg = R+( mask/256 * R-(Ximg) ) - G ;  m = mu*m + alpha*dg + sum(rg parts) ; Ximg -= m
__global__ void dc_update_kernel(float2* __restrict__ Xpad, float2* __restrict__ m,
                                 const float2* __restrict__ rg, const float2* __restrict__ G,
                                 const float* __restrict__ mask,
                                 const float* __restrict__ alphas, const float* __restrict__ moms,
                                 int l){
    __shared__ float2 lds[2][256];
    __shared__ float2 tw[128];    // e^{+i 2pi k/256}
    int tid = threadIdx.x;
    int line = tid >> 7;
    int j = tid & 127;
    if (tid < 128){
        float s, c;
        sincosf(6.283185307179586f * (float)tid / 256.0f, &s, &c);
        tw[tid] = make_float2(c, s);
    }
    long gl = (long)blockIdx.x*2 + line;   // = t*256 + h
    int t = (int)(gl >> 8);
    int h = (int)(gl & 255);
    float2* src = Xpad + (long)t*VPLANE + VIOFF + (long)h*VSTRIDE;
    float2 xo0, xo1;
    {   // load with (-1)^n
        float sg = (j & 1) ? -1.f : 1.f;
        xo0 = src[j]; xo1 = src[j+128];
        lds[line][j]     = make_float2(xo0.x*sg, xo0.y*sg);
        lds[line][j+128] = make_float2(xo1.x*sg, xo1.y*sg);
    }
    __syncthreads();
    // FFT1: DIF, dir = -1 (conj tw), natural in -> bit-reversed out
    for (int s = 0; s < 8; s++){
        int half = 128 >> s;
        int pos = j & (half-1);
        int grp = j >> (7-s);
        int i0 = (grp << (8-s)) + pos;
        int i1 = i0 + half;
        float2 u = lds[line][i0], v = lds[line][i1];
        float2 w = tw[pos << s]; w.y = -w.y;
        lds[line][i0] = make_float2(u.x+v.x, u.y+v.y);
        float2 d = make_float2(u.x-v.x, u.y-v.y);
        lds[line][i1] = cmulf(d, w);
        __syncthreads();
    }
    // middle: multiply by mask(natural k)/256; (-1)^k signs cancel between passes
    {
        int k1 = __brev((unsigned)j) >> 24;
        int k2 = __brev((unsigned)(j+128)) >> 24;
        float mv1 = mask[t*256 + k1] * (1.0f/256.0f);
        float mv2 = mask[t*256 + k2] * (1.0f/256.0f);
        float2 a = lds[line][j], b = lds[line][j+128];
        lds[line][j]     = make_float2(a.x*mv1, a.y*mv1);
        lds[line][j+128] = make_float2(b.x*mv2, b.y*mv2);
    }
    __syncthreads();
    // FFT2: DIT, dir = +1, bit-reversed in -> natural out
    for (int s = 0; s < 8; s++){
        int m2 = 1 << s;
        int pos = j & (m2-1);
        int grp = j >> s;
        int i0 = (grp << (s+1)) + pos;
        int i1 = i0 + m2;
        float2 u = lds[line][i0];
        float2 v = cmulf(lds[line][i1], tw[pos << (7-s)]);
        lds[line][i0] = make_float2(u.x+v.x, u.y+v.y);
        lds[line][i1] = make_float2(u.x-v.x, u.y-v.y);
        __syncthreads();
    }
    float a  = alphas[l];
    float mu = moms[l];
    float sg = (j & 1) ? -1.f : 1.f;
    #pragma unroll
    for (int half = 0; half < 2; half++){
        int k = j + half*128;
        long idx = gl*256 + k;
        float2 d = lds[line][k];
        d = make_float2(d.x*sg, d.y*sg);
        float2 g = G[idx];
        float2 r0 = rg[idx],          r1 = rg[idx + NPIX];
        float2 r2 = rg[idx + 2*NPIX], r3 = rg[idx + 3*NPIX];
        float rx = (r0.x + r1.x) + (r2.x + r3.x);
        float ry = (r0.y + r1.y) + (r2.y + r3.y);
        float2 grad = make_float2(fmaf(a, d.x - g.x, rx), fmaf(a, d.y - g.y, ry));
        float2 mm;
        if (l == 0){
            mm = grad;                       // m starts at zero; skip poisoned read
        } else {
            float2 mv = m[idx];
            mm = make_float2(fmaf(mu, mv.x, grad.x), fmaf(mu, mv.y, grad.y));
        }
        m[idx] = mm;
        float2 xo = half ? xo1 : xo0;
        src[k] = make_float2(xo.x - mm.x, xo.y - mm.y);
    }
}

// ---------------- output: stack(real, imag)*norm (reads padded Ximg) ------------
__global__ void output_kernel(const float2* __restrict__ Xpad, const float* __restrict__ sums,
                              float* __restrict__ out){
    int i = blockIdx.x*256 + threadIdx.x;
    int t = i >> 16;
    int p = i & 65535;
    int h = p >> 8, w = p & 255;
    float norm = sqrtf(sums[0]/sums[1]);
    float2 v = Xpad[(long)t*VPLANE + VIOFF + h*VSTRIDE + w];
    out[2*i]   = v.x * norm;
    out[2*i+1] = v.y * norm;
}

extern "C" void kernel_launch(void* const* d_in, const int* in_sizes, int n_in,
                              void* d_out, int out_size, void* d_ws, size_t ws_size,
                              hipStream_t stream){
    const float* Xr    = (const float*)d_in[0];
    const float* Xi    = (const float*)d_in[1];
    const float* mask  = (const float*)d_in[2];
    const float* kr    = (const float*)d_in[3];
    const float* ki    = (const float*)d_in[4];
    const float* knots = (const float*)d_in[5];
    const float* alph  = (const float*)d_in[6];
    const float* moms  = (const float*)d_in[7];
    const float* k0    = (const float*)d_in[8];

    float*  ws   = (float*)d_ws;
    float*  sums = ws;                        // 2 floats used (pad to 16)
    float*  Wf   = ws + 16;                   // 8*121*48 floats
    float*  Wa   = Wf + 8*121*48;
    float2* Xks  = (float2*)(Wa + 8*121*48);
    float2* mbuf = Xks  + NPIX;
    float2* G    = mbuf + NPIX;
    float2* rg   = G    + NPIX;               // 4*NPIX partials; first NPIX doubles as init tmp
    float2* Xpad = rg   + 4*NPIX;             // 6 * VPLANE, padded image
    float2* V    = Xpad + TT*VPLANE;          // 144 * VPLANE, padded V (contiguous after Xpad)

    const float OS = 1.0f/16.0f;              // ortho scale per 1D pass

    hipMemsetAsync(sums, 0, 2*sizeof(float), stream);
    halo_zero_kernel<<<(TOT_PLANES*HALO_PER_PLANE + 255)/256, 256, 0, stream>>>(Xpad);

    repack_kernel<<<(8*121*24 + 255)/256, 256, 0, stream>>>(kr, ki, Wf, Wa);
    reduce_kernel<<<384, 256, 0, stream>>>(Xr, Xi, mask, sums);
    normalize_kernel<<<NPIX/256, 256, 0, stream>>>(Xr, Xi, sums, Xks);

    // init: Xpad = k2i(Xks)*k0 (padded) ; G = k2i(Xks)
    fft_row_kernel<<<TT*128, 256, 0, stream>>>(Xks, rg, +1.0f, OS);
    fft_col_kernel<<<TT*(256/CPB), 256, 0, stream>>>(rg, Xpad, G, +1.0f, OS, k0);

    for (int l = 0; l < 8; l++){
        conv_fwd_act_kernel<<<dim3(16,16,12), 256, 0, stream>>>(
            Xpad, Wf + (long)l*121*48, knots + (long)l*KN*FC, V);
        conv_adj_kernel<<<dim3(16,8,4*TT), 256, 0, stream>>>(V, Wa + (long)l*24*242, rg);
        dc_update_kernel<<<TT*128, 256, 0, stream>>>(Xpad, mbuf, rg, G, mask, alph, moms, l);
    }

    output_kernel<<<NPIX/256, 256, 0, stream>>>(Xpad, sums, (float*)d_out);
}